// Round 12
// baseline (1744.254 us; speedup 1.0000x reference)
//
#include <hip/hip_runtime.h>

#define DEVI static __device__ __forceinline__

constexpr int B = 8;
constexpr int N0 = 4096;
constexpr int KNB = 64;

typedef float f32x2 __attribute__((ext_vector_type(2)));
typedef float f32x4 __attribute__((ext_vector_type(4)));
typedef short bf16x8 __attribute__((ext_vector_type(8)));

// d2 exactly as numpy: ((dx*dx + dy*dy) + dz*dz), no FMA contraction.
DEVI float dist2f(float ax, float ay, float az, float bx, float by, float bz) {
#pragma clang fp contract(off)
  float dx = ax - bx;
  float dy = ay - by;
  float dz = az - bz;
  return (dx * dx + dy * dy) + dz * dz;
}
DEVI f32x2 dist2v(f32x2 ax, f32x2 ay, f32x2 az, float bx, float by, float bz) {
#pragma clang fp contract(off)
  f32x2 dx = ax - bx;
  f32x2 dy = ay - by;
  f32x2 dz = az - bz;
  return (dx * dx + dy * dy) + dz * dz;
}

DEVI unsigned long long packMinKey(float v, int i) {
  return ((unsigned long long)__float_as_uint(v) << 32) | (unsigned int)i;
}

// ---- u64 max wave-64 reduction (DPP, VALU pipe); broadcast via readlane(63).
template <int CTRL, int RM>
DEVI unsigned long long dppMaxU64(unsigned long long k) {
  unsigned lo = (unsigned)k, hi = (unsigned)(k >> 32);
  unsigned mlo = (unsigned)__builtin_amdgcn_update_dpp((int)lo, (int)lo, CTRL, RM, 0xf, false);
  unsigned mhi = (unsigned)__builtin_amdgcn_update_dpp((int)hi, (int)hi, CTRL, RM, 0xf, false);
  unsigned long long o = ((unsigned long long)mhi << 32) | mlo;
  return (k > o) ? k : o;
}
DEVI unsigned long long waveReduceMaxU64(unsigned long long k) {
  k = dppMaxU64<0x111, 0xf>(k);  // row_shr:1
  k = dppMaxU64<0x112, 0xf>(k);  // row_shr:2
  k = dppMaxU64<0x114, 0xf>(k);  // row_shr:4
  k = dppMaxU64<0x118, 0xf>(k);  // row_shr:8
  k = dppMaxU64<0x142, 0xa>(k);  // row_bcast:15 -> rows 1,3
  k = dppMaxU64<0x143, 0xc>(k);  // row_bcast:31 -> rows 2,3
  unsigned lo = (unsigned)__builtin_amdgcn_readlane((int)(unsigned)k, 63);
  unsigned hi = (unsigned)__builtin_amdgcn_readlane((int)(unsigned)(k >> 32), 63);
  return ((unsigned long long)hi << 32) | lo;
}

// ---- bf16 split helpers (RNE) ----
DEVI unsigned short bfhi(float x) {
  unsigned u = __float_as_uint(x);
  return (unsigned short)((u + 0x7FFFu + ((u >> 16) & 1u)) >> 16);
}
DEVI float bf2f(unsigned short h) { return __uint_as_float(((unsigned)h) << 16); }
DEVI void mkfrag(const float* p, bf16x8& hi, bf16x8& lo) {
#pragma unroll
  for (int e = 0; e < 8; ++e) {
    float x = p[e];
    unsigned short h = bfhi(x);
    float r = x - bf2f(h);
    unsigned short l2 = bfhi(r);
    hi[e] = (short)h;
    lo[e] = (short)l2;
  }
}

// ---- device-scope ordering primitives (per-XCD L2 non-coherent -> AGENT) ----
DEVI void waitFlag(int* f) {
  while (__hip_atomic_load(f, __ATOMIC_ACQUIRE, __HIP_MEMORY_SCOPE_AGENT) == 0)
    __builtin_amdgcn_s_sleep(8);
}
DEVI void waitCount(int* f, int target) {
  while (__hip_atomic_load(f, __ATOMIC_ACQUIRE, __HIP_MEMORY_SCOPE_AGENT) < target)
    __builtin_amdgcn_s_sleep(8);
}
DEVI void setFlag(int* f) {
  __hip_atomic_store(f, 1, __ATOMIC_RELEASE, __HIP_MEMORY_SCOPE_AGENT);
}
DEVI void bumpCount(int* f) {
  __hip_atomic_fetch_add(f, 1, __ATOMIC_RELEASE, __HIP_MEMORY_SCOPE_AGENT);
}

// ================= device bodies ======

DEVI void x0_body(const int* __restrict__ feat, const float* __restrict__ emb,
                  const float* __restrict__ pid, float* __restrict__ x0buf,
                  int bx, int t) {
  int gid = bx * 256 + t;
  if (gid >= B * N0 * 32) return;
  int c = gid & 31;
  int bn = gid >> 5;
  int n = bn & (N0 - 1);
  int f = feat[bn];
  float v = emb[f * 32 + c];
  if (n < 1024) v += pid[n * 32 + c];
  x0buf[gid] = v;
}

// ---- weight packing into MFMA-B fragment order ----
DEVI void pack_body(int gid, const float* __restrict__ W, int Kreal, int KS,
                    int N, unsigned short* __restrict__ hi,
                    unsigned short* __restrict__ lo) {
  int e = gid & 7;
  int l = (gid >> 3) & 63;
  int rest = gid >> 9;
  int ks = rest % KS;
  int nt = rest / KS;
  int n = nt * 16 + (l & 15);
  int k = ks * 32 + (l >> 4) * 8 + e;
  float val = (k < Kreal) ? W[(size_t)k * N + n] : 0.f;
  unsigned short h = bfhi(val);
  float r = val - bf2f(h);
  hi[gid] = h;
  lo[gid] = bfhi(r);
}

// ---- farthest point sampling (selection semantics == jnp.argmax) ----
// Direct global pos_out writes in-loop (R6 measured: free). smem = posl + redk.
template <int NPTS, int M, int BLK>
DEVI void fps_body(char* smem, const float* __restrict__ pos,
                   float* __restrict__ pos_out, int b, int t) {
  constexpr int EPT = NPTS / BLK;
  constexpr int EP2 = EPT / 2;
  constexpr int NW = BLK / 64;
  float4* posl = (float4*)smem;
  unsigned long long* redk =
      (unsigned long long*)(smem + (size_t)NPTS * 16);  // [2][NW]
  const float* pb = pos + (size_t)b * NPTS * 3;
  f32x2 px[EP2], py[EP2], pz[EP2], d[EP2];
#pragma unroll
  for (int e = 0; e < EP2; ++e) {
    int i0 = t + (2 * e) * BLK;
    int i1 = t + (2 * e + 1) * BLK;
    float x0 = pb[i0 * 3 + 0], y0 = pb[i0 * 3 + 1], z0 = pb[i0 * 3 + 2];
    float x1 = pb[i1 * 3 + 0], y1 = pb[i1 * 3 + 1], z1 = pb[i1 * 3 + 2];
    px[e] = (f32x2){x0, x1};
    py[e] = (f32x2){y0, y1};
    pz[e] = (f32x2){z0, z1};
    posl[i0] = make_float4(x0, y0, z0, 0.f);
    posl[i1] = make_float4(x1, y1, z1, 0.f);
  }
  float sx = pb[0], sy = pb[1], sz = pb[2];
  if (t == 0) {
    pos_out[(size_t)(b * M) * 3 + 0] = sx;
    pos_out[(size_t)(b * M) * 3 + 1] = sy;
    pos_out[(size_t)(b * M) * 3 + 2] = sz;
  }
  f32x2 m2 = (f32x2){-1.f, -1.f};
#pragma unroll
  for (int e = 0; e < EP2; ++e) {
    d[e] = dist2v(px[e], py[e], pz[e], sx, sy, sz);
    m2.x = fmaxf(m2.x, d[e].x);
    m2.y = fmaxf(m2.y, d[e].y);
  }
  for (int it = 1; it < M; ++it) {
    const float lm = fmaxf(m2.x, m2.y);  // lane max (>=1 element matches)
    unsigned cand = 0xffffffffu;
#pragma unroll
    for (int e = 0; e < EP2; ++e) {
      unsigned c0 = (d[e].x == lm) ? (unsigned)(t + (2 * e) * BLK) : 0xffffffffu;
      unsigned c1 = (d[e].y == lm) ? (unsigned)(t + (2 * e + 1) * BLK) : 0xffffffffu;
      unsigned cc = c0 < c1 ? c0 : c1;
      cand = cand < cc ? cand : cc;
    }
    unsigned long long k =
        ((unsigned long long)__float_as_uint(lm) << 32) |
        (unsigned)(0x7fffffffu - cand);
    k = waveReduceMaxU64(k);
    unsigned sel;
    if constexpr (NW > 1) {
      if ((t & 63) == 0) redk[(it & 1) * NW + (t >> 6)] = k;
      __syncthreads();  // double-buffered -> single barrier race-free
      unsigned long long kk = redk[(it & 1) * NW + 0];
#pragma unroll
      for (int w = 1; w < NW; ++w) {
        unsigned long long o = redk[(it & 1) * NW + w];
        kk = (kk > o) ? kk : o;
      }
      sel = 0x7fffffffu - (unsigned)(kk & 0xffffffffULL);
    } else {
      sel = 0x7fffffffu - (unsigned)(k & 0xffffffffULL);
    }
    float4 sp = posl[sel];  // LDS broadcast
    if (t == 0) {
      pos_out[(size_t)(b * M + it) * 3 + 0] = sp.x;
      pos_out[(size_t)(b * M + it) * 3 + 1] = sp.y;
      pos_out[(size_t)(b * M + it) * 3 + 2] = sp.z;
    }
    f32x2 mm = (f32x2){-1.f, -1.f};
#pragma unroll
    for (int e = 0; e < EP2; ++e) {
      f32x2 nd = dist2v(px[e], py[e], pz[e], sp.x, sp.y, sp.z);
      d[e].x = fminf(d[e].x, nd.x);
      d[e].y = fminf(d[e].y, nd.y);
      mm.x = fmaxf(mm.x, d[e].x);
      mm.y = fmaxf(mm.y, d[e].y);
    }
    m2 = mm;
  }
}

// ---- radius neighbors (<=64 nearest within r), rank-select overflow ----
template <int NPTS, int M>
DEVI void radius_body(char* smem, const float* __restrict__ pos,
                      const float* __restrict__ pos_s, float r2,
                      int* __restrict__ nbr, int* __restrict__ cnt, int blk,
                      int t) {
  unsigned long long* candkey = (unsigned long long*)smem;
  int* ctrp = (int*)(smem + (size_t)NPTS * 8);
  const int b = blk / M;
  const float* pb = pos + (size_t)b * NPTS * 3;
  const float cx = pos_s[(size_t)blk * 3 + 0];
  const float cy = pos_s[(size_t)blk * 3 + 1];
  const float cz = pos_s[(size_t)blk * 3 + 2];
  if (t == 0) *ctrp = 0;
  __syncthreads();
  for (int j = t; j < NPTS; j += 256) {
    float d2 = dist2f(pb[j * 3 + 0], pb[j * 3 + 1], pb[j * 3 + 2], cx, cy, cz);
    if (d2 <= r2) {
      int p = atomicAdd(ctrp, 1);
      candkey[p] = packMinKey(d2, j);
      if (p < KNB) nbr[(size_t)blk * KNB + p] = j;
    }
  }
  __syncthreads();
  const int c = *ctrp;
  if (c <= KNB) {
    if (t == 0) cnt[blk] = c;
    return;
  }
  for (int s = t; s < c; s += 256) {
    unsigned long long mykey = candkey[s];
    int rank = 0;
#pragma unroll 4
    for (int j = 0; j < c; ++j) {
      rank += (candkey[j] < mykey) ? 1 : 0;
    }
    if (rank < KNB)
      nbr[(size_t)blk * KNB + rank] = (int)(unsigned)(mykey & 0xffffffffULL);
  }
  if (t == 0) cnt[blk] = KNB;
}

// ---- stage 1 conv: 35 -> 64 -> 64 -> 64, max over nbrs (4 slots x 64ch) ----
DEVI void conv1_body(char* smem, const float* __restrict__ x0buf,
                     const float* __restrict__ pos,
                     const float* __restrict__ pos_s,
                     const int* __restrict__ nbr, const int* __restrict__ cntp,
                     const float* __restrict__ w0, const float* __restrict__ b0,
                     const float* __restrict__ w1, const float* __restrict__ b1,
                     const float* __restrict__ w2, const float* __restrict__ b2,
                     float* __restrict__ x1, int blk, int t) {
  float(*ins)[36] = (float(*)[36])smem;
  float(*hh)[65] = (float(*)[65])(smem + 576);
  float(*sred)[65] = (float(*)[65])(smem + 1616);
  const int slot = t >> 6;
  const int ch = t & 63;
  const int b = blk >> 10;
  const int c = cntp[blk];
  const float cx = pos_s[(size_t)blk * 3 + 0];
  const float cy = pos_s[(size_t)blk * 3 + 1];
  const float cz = pos_s[(size_t)blk * 3 + 2];
  float best = -__builtin_inff();
  for (int r0 = 0; r0 < c; r0 += 4) {
    const int r = r0 + slot;
    const bool act = r < c;
    const int j = nbr[(size_t)blk * KNB + (act ? r : 0)];
    if (ch < 32) {
      ins[slot][ch] = x0buf[((size_t)(b * N0) + j) * 32 + ch];
    } else if (ch < 35) {
      float pv = pos[((size_t)(b * N0) + j) * 3 + (ch - 32)];
      float cv = (ch == 32) ? cx : (ch == 33) ? cy : cz;
      ins[slot][ch] = pv - cv;
    }
    __syncthreads();
    float v = b0[ch];
#pragma unroll
    for (int i = 0; i < 35; ++i) v = fmaf(ins[slot][i], w0[i * 64 + ch], v);
    v = fmaxf(v, 0.f);
    hh[slot][ch] = v;
    __syncthreads();
    float v2 = b1[ch];
#pragma unroll
    for (int i = 0; i < 64; ++i) v2 = fmaf(hh[slot][i], w1[i * 64 + ch], v2);
    v2 = fmaxf(v2, 0.f);
    __syncthreads();
    hh[slot][ch] = v2;
    __syncthreads();
    float v3 = b2[ch];
#pragma unroll
    for (int i = 0; i < 64; ++i) v3 = fmaf(hh[slot][i], w2[i * 64 + ch], v3);
    if (act) best = fmaxf(best, v3);
    __syncthreads();
  }
  sred[slot][ch] = best;
  __syncthreads();
  if (t < 64) {
    float v = sred[0][t];
#pragma unroll
    for (int s = 1; s < 4; ++s) v = fmaxf(v, sred[s][t]);
    x1[(size_t)blk * 64 + t] = v;
  }
}

// ---- stage 2 conv via split-bf16 MFMA: 67 -> 128 -> 128 -> 256 ----
DEVI void conv2_mfma_body(char* smem, const float* __restrict__ x1,
                          const float* __restrict__ pos1,
                          const float* __restrict__ pos2,
                          const int* __restrict__ nbr,
                          const int* __restrict__ cntp,
                          const unsigned short* __restrict__ w0h,
                          const float* __restrict__ b0,
                          const unsigned short* __restrict__ w1h,
                          const float* __restrict__ b1,
                          const unsigned short* __restrict__ w2h,
                          const float* __restrict__ b2,
                          float* __restrict__ x2, int blk, int t) {
  float(*h1)[132] = (float(*)[132])smem;
  float(*h2)[132] = (float(*)[132])(smem + 33792);
  float* red = (float*)smem;  // alias h1 (dead after L2 reads)
  const int b = blk >> 8;
  const int c = cntp[blk];
  const int w = t >> 6;
  const int lane = t & 63;
  const int cb = lane & 15;
  const int kb = lane >> 4;
  const int mrow = w * 16 + cb;  // A-fragment row
  const int jrow = nbr[(size_t)blk * KNB + (mrow < c ? mrow : c - 1)];
  const float* xrow = x1 + ((size_t)(b * 1024) + jrow) * 64;
  const float cx = pos2[(size_t)blk * 3 + 0];
  const float cy = pos2[(size_t)blk * 3 + 1];
  const float cz = pos2[(size_t)blk * 3 + 2];

  f32x4 acc1[8];
#pragma unroll
  for (int nt = 0; nt < 8; ++nt) acc1[nt] = (f32x4){0.f, 0.f, 0.f, 0.f};
#pragma unroll
  for (int ks = 0; ks < 2; ++ks) {
    float xv[8];
    *(float4*)&xv[0] = *(const float4*)&xrow[ks * 32 + kb * 8];
    *(float4*)&xv[4] = *(const float4*)&xrow[ks * 32 + kb * 8 + 4];
    bf16x8 ahi, alo;
    mkfrag(xv, ahi, alo);
#pragma unroll
    for (int nt = 0; nt < 8; ++nt) {
      size_t off = ((size_t)(nt * 3 + ks) * 64 + lane) * 8;
      bf16x8 bhi = *(const bf16x8*)(w0h + off);
      acc1[nt] = __builtin_amdgcn_mfma_f32_16x16x32_bf16(ahi, bhi, acc1[nt], 0, 0, 0);
      acc1[nt] = __builtin_amdgcn_mfma_f32_16x16x32_bf16(alo, bhi, acc1[nt], 0, 0, 0);
    }
  }
  {
    float xv[8] = {0.f, 0.f, 0.f, 0.f, 0.f, 0.f, 0.f, 0.f};
    if (kb == 0) {
      xv[0] = pos1[((size_t)(b * 1024) + jrow) * 3 + 0] - cx;
      xv[1] = pos1[((size_t)(b * 1024) + jrow) * 3 + 1] - cy;
      xv[2] = pos1[((size_t)(b * 1024) + jrow) * 3 + 2] - cz;
    }
    bf16x8 ahi, alo;
    mkfrag(xv, ahi, alo);
#pragma unroll
    for (int nt = 0; nt < 8; ++nt) {
      size_t off = ((size_t)(nt * 3 + 2) * 64 + lane) * 8;
      bf16x8 bhi = *(const bf16x8*)(w0h + off);
      acc1[nt] = __builtin_amdgcn_mfma_f32_16x16x32_bf16(ahi, bhi, acc1[nt], 0, 0, 0);
      acc1[nt] = __builtin_amdgcn_mfma_f32_16x16x32_bf16(alo, bhi, acc1[nt], 0, 0, 0);
    }
  }
  {
    const int mw = w * 16 + kb * 4;
#pragma unroll
    for (int nt = 0; nt < 8; ++nt) {
      float bias = b0[nt * 16 + cb];
#pragma unroll
      for (int r = 0; r < 4; ++r)
        h1[mw + r][nt * 16 + cb] = fmaxf(acc1[nt][r] + bias, 0.f);
    }
  }

  f32x4 acc2[8];
#pragma unroll
  for (int nt = 0; nt < 8; ++nt) acc2[nt] = (f32x4){0.f, 0.f, 0.f, 0.f};
#pragma unroll
  for (int ks = 0; ks < 4; ++ks) {
    bf16x8 ahi, alo;
    mkfrag(&h1[mrow][ks * 32 + kb * 8], ahi, alo);
#pragma unroll
    for (int nt = 0; nt < 8; ++nt) {
      size_t off = ((size_t)(nt * 4 + ks) * 64 + lane) * 8;
      bf16x8 bhi = *(const bf16x8*)(w1h + off);
      acc2[nt] = __builtin_amdgcn_mfma_f32_16x16x32_bf16(ahi, bhi, acc2[nt], 0, 0, 0);
      acc2[nt] = __builtin_amdgcn_mfma_f32_16x16x32_bf16(alo, bhi, acc2[nt], 0, 0, 0);
    }
  }
  {
    const int mw = w * 16 + kb * 4;
#pragma unroll
    for (int nt = 0; nt < 8; ++nt) {
      float bias = b1[nt * 16 + cb];
#pragma unroll
      for (int r = 0; r < 4; ++r)
        h2[mw + r][nt * 16 + cb] = fmaxf(acc2[nt][r] + bias, 0.f);
    }
  }

  f32x4 acc3[16];
#pragma unroll
  for (int nt = 0; nt < 16; ++nt) acc3[nt] = (f32x4){0.f, 0.f, 0.f, 0.f};
#pragma unroll
  for (int ks = 0; ks < 4; ++ks) {
    bf16x8 ahi, alo;
    mkfrag(&h2[mrow][ks * 32 + kb * 8], ahi, alo);
#pragma unroll
    for (int nt = 0; nt < 16; ++nt) {
      size_t off = ((size_t)(nt * 4 + ks) * 64 + lane) * 8;
      bf16x8 bhi = *(const bf16x8*)(w2h + off);
      acc3[nt] = __builtin_amdgcn_mfma_f32_16x16x32_bf16(ahi, bhi, acc3[nt], 0, 0, 0);
      acc3[nt] = __builtin_amdgcn_mfma_f32_16x16x32_bf16(alo, bhi, acc3[nt], 0, 0, 0);
    }
  }
  __syncthreads();  // all h1 reads done before red (aliases h1)
  {
    const int mw = w * 16 + kb * 4;
#pragma unroll
    for (int nt = 0; nt < 16; ++nt) {
      float bias = b2[nt * 16 + cb];
      float mx = -__builtin_inff();
#pragma unroll
      for (int r = 0; r < 4; ++r) {
        if (mw + r < c) mx = fmaxf(mx, acc3[nt][r] + bias);
      }
      red[(w * 4 + kb) * 256 + nt * 16 + cb] = mx;
    }
  }
  __syncthreads();
  {
    float v = red[t];
#pragma unroll
    for (int g = 1; g < 16; ++g) v = fmaxf(v, red[g * 256 + t]);
    x2[(size_t)blk * 256 + t] = v;
  }
}

// ================= mega kernel ====================================

constexpr int PK_T0 = 16 * 9 * 64 * 8;   // conv3 L1
constexpr int PK_T1 = 32 * 8 * 64 * 8;   // conv3 L2
constexpr int PK_T2 = 32 * 16 * 64 * 8;  // conv3 L3
constexpr int PK_U0 = 8 * 3 * 64 * 8;    // conv2 L1
constexpr int PK_U1 = 8 * 4 * 64 * 8;    // conv2 L2
constexpr int PK_U2 = 16 * 4 * 64 * 8;   // conv2 L3
constexpr int PK_TOTAL = PK_T0 + PK_T1 + PK_T2 + PK_U0 + PK_U1 + PK_U2;
constexpr int PK_BLOCKS = PK_TOTAL / 256;  // 2064

// flag layout (ints)
constexpr int FL_F1 = 0;                    // 8: fps1 done per batch
constexpr int FL_F2 = 8;                    // 8: fps2
constexpr int FL_F3 = 16;                   // 8: fps3
constexpr int FL_CX0 = 24;                  // x0 block counter
constexpr int FL_CPK = 25;                  // pack block counter
constexpr int FL_CC1 = 26;                  // conv1 block counter
constexpr int FL_R1 = 28;                   // 8192: radius1 per center
constexpr int FL_R2 = 28 + 8192;            // 2048: radius2 per center
constexpr int FL_TOTAL = 28 + 8192 + 2048;  // 10268 ints

// Block roles in dispatch order (every wait references a LOWER block index ->
// deadlock-free: producers dispatch/resident first).
constexpr int MG_FPS1 = 0;                    // 8
constexpr int MG_X0 = MG_FPS1 + 8;            // 4096
constexpr int MG_PACK = MG_X0 + 4096;         // 2064
constexpr int MG_FPS2 = MG_PACK + PK_BLOCKS;  // 8
constexpr int MG_RAD1 = MG_FPS2 + 8;          // 8192
constexpr int MG_CONV1 = MG_RAD1 + 8192;      // 8192
constexpr int MG_FPS3 = MG_CONV1 + 8192;      // 8
constexpr int MG_RAD2 = MG_FPS3 + 8;          // 2048
constexpr int MG_RAD3 = MG_RAD2 + 2048;       // 512
constexpr int MG_CONV2 = MG_RAD3 + 512;       // 2048
constexpr int MG_TOTAL = MG_CONV2 + 2048;     // 27176

__global__ void __launch_bounds__(256) mega_kernel(
    int* __restrict__ fl,
    const float* __restrict__ pos, float* __restrict__ pos1,
    float* __restrict__ pos2, float* __restrict__ pos3,
    const int* __restrict__ feat, const float* __restrict__ emb,
    const float* __restrict__ pid, float* __restrict__ x0buf,
    const float* __restrict__ s3w0, const float* __restrict__ s3w1,
    const float* __restrict__ s3w2, const float* __restrict__ s2w0,
    const float* __restrict__ s2w1, const float* __restrict__ s2w2,
    unsigned short* __restrict__ w0h, unsigned short* __restrict__ w0l,
    unsigned short* __restrict__ w1h, unsigned short* __restrict__ w1l,
    unsigned short* __restrict__ w2h, unsigned short* __restrict__ w2l,
    unsigned short* __restrict__ v0h, unsigned short* __restrict__ v0l,
    unsigned short* __restrict__ v1h, unsigned short* __restrict__ v1l,
    unsigned short* __restrict__ v2h, unsigned short* __restrict__ v2l,
    float r2a, float r2b, float r2c,
    int* __restrict__ nbr1, int* __restrict__ cnt1,
    int* __restrict__ nbr2, int* __restrict__ cnt2,
    int* __restrict__ nbr3, int* __restrict__ cnt3,
    const float* __restrict__ s1w0, const float* __restrict__ s1b0,
    const float* __restrict__ s1w1, const float* __restrict__ s1b1,
    const float* __restrict__ s1w2, const float* __restrict__ s1b2,
    float* __restrict__ x1,
    const float* __restrict__ s2b0, const float* __restrict__ s2b1,
    const float* __restrict__ s2b2, float* __restrict__ x2) {
  __shared__ __attribute__((aligned(16))) char smem[67584];
  const int t = threadIdx.x;
  int bx = blockIdx.x;
  if (bx < MG_X0) {  // fps1
    fps_body<4096, 1024, 256>(smem, pos, pos1, bx, t);
    __syncthreads();
    if (t == 0) setFlag(fl + FL_F1 + bx);
    return;
  }
  if (bx < MG_PACK) {  // x0
    x0_body(feat, emb, pid, x0buf, bx - MG_X0, t);
    __syncthreads();
    if (t == 0) bumpCount(fl + FL_CX0);
    return;
  }
  if (bx < MG_FPS2) {  // weight packing
    int gid = (bx - MG_PACK) * 256 + t;
    if (gid < PK_T0) { pack_body(gid, s3w0, 259, 9, 256, w0h, w0l); }
    else if ((gid -= PK_T0) < PK_T1) { pack_body(gid, s3w1, 256, 8, 512, w1h, w1l); }
    else if ((gid -= PK_T1) < PK_T2) { pack_body(gid, s3w2, 512, 16, 512, w2h, w2l); }
    else if ((gid -= PK_T2) < PK_U0) { pack_body(gid, s2w0, 67, 3, 128, v0h, v0l); }
    else if ((gid -= PK_U0) < PK_U1) { pack_body(gid, s2w1, 128, 4, 128, v1h, v1l); }
    else { pack_body(gid - PK_U1, s2w2, 128, 4, 256, v2h, v2l); }
    __syncthreads();
    if (t == 0) bumpCount(fl + FL_CPK);
    return;
  }
  if (bx < MG_RAD1) {  // fps2
    int b = bx - MG_FPS2;
    if (t == 0) waitFlag(fl + FL_F1 + b);
    __syncthreads();
    if (t < 64) fps_body<1024, 256, 64>(smem, pos1, pos2, b, t);
    __syncthreads();
    if (t == 0) setFlag(fl + FL_F2 + b);
    return;
  }
  if (bx < MG_CONV1) {  // radius1, center i
    int i = bx - MG_RAD1;
    if (t == 0) waitFlag(fl + FL_F1 + (i >> 10));
    __syncthreads();
    radius_body<4096, 1024>(smem, pos, pos1, r2a, nbr1, cnt1, i, t);
    __syncthreads();
    if (t == 0) setFlag(fl + FL_R1 + i);
    return;
  }
  if (bx < MG_FPS3) {  // conv1, center i
    int i = bx - MG_CONV1;
    if (t == 0) {
      waitFlag(fl + FL_R1 + i);
      waitCount(fl + FL_CX0, 4096);
    }
    __syncthreads();
    conv1_body(smem, x0buf, pos, pos1, nbr1, cnt1, s1w0, s1b0, s1w1, s1b1,
               s1w2, s1b2, x1, i, t);
    __syncthreads();
    if (t == 0) bumpCount(fl + FL_CC1);
    return;
  }
  if (bx < MG_RAD2) {  // fps3
    int b = bx - MG_FPS3;
    if (t == 0) waitFlag(fl + FL_F2 + b);
    __syncthreads();
    if (t < 64) fps_body<256, 64, 64>(smem, pos2, pos3, b, t);
    __syncthreads();
    if (t == 0) setFlag(fl + FL_F3 + b);
    return;
  }
  if (bx < MG_RAD3) {  // radius2, center i
    int i = bx - MG_RAD2;
    if (t == 0) waitFlag(fl + FL_F2 + (i >> 8));
    __syncthreads();
    radius_body<1024, 256>(smem, pos1, pos2, r2b, nbr2, cnt2, i, t);
    __syncthreads();
    if (t == 0) setFlag(fl + FL_R2 + i);
    return;
  }
  if (bx < MG_CONV2) {  // radius3, center i (conv3 is a separate kernel)
    int i = bx - MG_RAD3;
    if (t == 0) waitFlag(fl + FL_F3 + (i >> 6));
    __syncthreads();
    radius_body<256, 64>(smem, pos2, pos3, r2c, nbr3, cnt3, i, t);
    return;
  }
  {  // conv2, center i
    int i = bx - MG_CONV2;
    if (t == 0) {
      waitFlag(fl + FL_R2 + i);
      waitCount(fl + FL_CC1, 8192);
      waitCount(fl + FL_CPK, PK_BLOCKS);
    }
    __syncthreads();
    conv2_mfma_body(smem, x1, pos1, pos2, nbr2, cnt2, v0h, s2b0, v1h, s2b1,
                    v2h, s2b2, x2, i, t);
    return;
  }
}

// ---------------- stage 3 conv via split-bf16 MFMA (separate kernel) --------
__global__ void __launch_bounds__(256) conv3_mfma(
    const float* __restrict__ x2, const float* __restrict__ pos2,
    const float* __restrict__ pos3, const int* __restrict__ nbr,
    const int* __restrict__ cntp,
    const unsigned short* __restrict__ w0h, const float* __restrict__ b0,
    const unsigned short* __restrict__ w1h, const float* __restrict__ b1,
    const unsigned short* __restrict__ w2h, const float* __restrict__ b2,
    float* __restrict__ out) {
  __shared__ __attribute__((aligned(16))) float h1s[64 * 268];
  __shared__ __attribute__((aligned(16))) float h2cs[64 * 140];
  const int blk = blockIdx.x;
  const int t = threadIdx.x;
  const int b = blk >> 6;
  const int c = cntp[blk];
  const int w = t >> 6;
  const int lane = t & 63;
  const int cb = lane & 15;
  const int kb = lane >> 4;
  const float cx = pos3[(size_t)blk * 3 + 0];
  const float cy = pos3[(size_t)blk * 3 + 1];
  const float cz = pos3[(size_t)blk * 3 + 2];
  const int mrow = w * 16 + cb;
  const int jrow = nbr[(size_t)blk * KNB + (mrow < c ? mrow : c - 1)];
  const float* xrow = x2 + ((size_t)(b * 256) + jrow) * 256;

  f32x4 acc1[16];
#pragma unroll
  for (int nt = 0; nt < 16; ++nt) acc1[nt] = (f32x4){0.f, 0.f, 0.f, 0.f};
#pragma unroll
  for (int ks = 0; ks < 8; ++ks) {
    float xv[8];
    *(float4*)&xv[0] = *(const float4*)&xrow[ks * 32 + kb * 8];
    *(float4*)&xv[4] = *(const float4*)&xrow[ks * 32 + kb * 8 + 4];
    bf16x8 ahi, alo;
    mkfrag(xv, ahi, alo);
#pragma unroll
    for (int nt = 0; nt < 16; ++nt) {
      size_t off = ((size_t)(nt * 9 + ks) * 64 + lane) * 8;
      bf16x8 bhi = *(const bf16x8*)(w0h + off);
      acc1[nt] = __builtin_amdgcn_mfma_f32_16x16x32_bf16(ahi, bhi, acc1[nt], 0, 0, 0);
      acc1[nt] = __builtin_amdgcn_mfma_f32_16x16x32_bf16(alo, bhi, acc1[nt], 0, 0, 0);
    }
  }
  {
    float xv[8] = {0.f, 0.f, 0.f, 0.f, 0.f, 0.f, 0.f, 0.f};
    if (kb == 0) {
      xv[0] = pos2[((size_t)(b * 256) + jrow) * 3 + 0] - cx;
      xv[1] = pos2[((size_t)(b * 256) + jrow) * 3 + 1] - cy;
      xv[2] = pos2[((size_t)(b * 256) + jrow) * 3 + 2] - cz;
    }
    bf16x8 ahi, alo;
    mkfrag(xv, ahi, alo);
#pragma unroll
    for (int nt = 0; nt < 16; ++nt) {
      size_t off = ((size_t)(nt * 9 + 8) * 64 + lane) * 8;
      bf16x8 bhi = *(const bf16x8*)(w0h + off);
      acc1[nt] = __builtin_amdgcn_mfma_f32_16x16x32_bf16(ahi, bhi, acc1[nt], 0, 0, 0);
      acc1[nt] = __builtin_amdgcn_mfma_f32_16x16x32_bf16(alo, bhi, acc1[nt], 0, 0, 0);
    }
  }
  {
    const int mw = w * 16 + kb * 4;
#pragma unroll
    for (int nt = 0; nt < 16; ++nt) {
      float bias = b0[nt * 16 + cb];
#pragma unroll
      for (int r = 0; r < 4; ++r)
        h1s[(mw + r) * 268 + nt * 16 + cb] = fmaxf(acc1[nt][r] + bias, 0.f);
    }
  }

  f32x4 acc3[32];
#pragma unroll
  for (int nt = 0; nt < 32; ++nt) acc3[nt] = (f32x4){0.f, 0.f, 0.f, 0.f};
  for (int ch = 0; ch < 4; ++ch) {
    f32x4 acc2[8];
#pragma unroll
    for (int nt = 0; nt < 8; ++nt) acc2[nt] = (f32x4){0.f, 0.f, 0.f, 0.f};
#pragma unroll
    for (int ks = 0; ks < 8; ++ks) {
      bf16x8 ahi, alo;
      mkfrag(&h1s[mrow * 268 + ks * 32 + kb * 8], ahi, alo);
#pragma unroll
      for (int nt = 0; nt < 8; ++nt) {
        size_t off = ((size_t)((ch * 8 + nt) * 8 + ks) * 64 + lane) * 8;
        bf16x8 bhi = *(const bf16x8*)(w1h + off);
        acc2[nt] = __builtin_amdgcn_mfma_f32_16x16x32_bf16(ahi, bhi, acc2[nt], 0, 0, 0);
        acc2[nt] = __builtin_amdgcn_mfma_f32_16x16x32_bf16(alo, bhi, acc2[nt], 0, 0, 0);
      }
    }
    {
      const int mw = w * 16 + kb * 4;
#pragma unroll
      for (int nt = 0; nt < 8; ++nt) {
        float bias = b1[ch * 128 + nt * 16 + cb];
#pragma unroll
        for (int r = 0; r < 4; ++r)
          h2cs[(mw + r) * 140 + nt * 16 + cb] = fmaxf(acc2[nt][r] + bias, 0.f);
      }
    }
#pragma unroll
    for (int ks3 = 0; ks3 < 4; ++ks3) {
      bf16x8 ahi, alo;
      mkfrag(&h2cs[mrow * 140 + ks3 * 32 + kb * 8], ahi, alo);
#pragma unroll
      for (int nt = 0; nt < 32; ++nt) {
        size_t off = ((size_t)(nt * 16 + ch * 4 + ks3) * 64 + lane) * 8;
        bf16x8 bhi = *(const bf16x8*)(w2h + off);
        acc3[nt] = __builtin_amdgcn_mfma_f32_16x16x32_bf16(ahi, bhi, acc3[nt], 0, 0, 0);
        acc3[nt] = __builtin_amdgcn_mfma_f32_16x16x32_bf16(alo, bhi, acc3[nt], 0, 0, 0);
      }
    }
  }

  __syncthreads();  // all h1s reads done before alias reuse
  float* redw = h1s;
  {
    const int mw = w * 16 + kb * 4;
#pragma unroll
    for (int nt = 0; nt < 32; ++nt) {
      float bias = b2[nt * 16 + cb];
      float mx = -__builtin_inff();
#pragma unroll
      for (int r = 0; r < 4; ++r) {
        if (mw + r < c) mx = fmaxf(mx, acc3[nt][r] + bias);
      }
      redw[(w * 4 + kb) * 512 + nt * 16 + cb] = mx;
    }
  }
  __syncthreads();
#pragma unroll
  for (int half = 0; half < 2; ++half) {
    int col = t + half * 256;
    float v = redw[col];
#pragma unroll
    for (int g = 1; g < 16; ++g) v = fmaxf(v, redw[g * 512 + col]);
    out[(size_t)blk * 512 + col] = v;
  }
}

extern "C" void kernel_launch(void* const* d_in, const int* in_sizes, int n_in,
                              void* d_out, int out_size, void* d_ws, size_t ws_size,
                              hipStream_t stream) {
  const int* feat = (const int*)d_in[0];
  const float* pos = (const float*)d_in[1];
  const float* emb = (const float*)d_in[2];
  const float* pid = (const float*)d_in[3];
  const float* s1w0 = (const float*)d_in[4];
  const float* s1b0 = (const float*)d_in[5];
  const float* s1w1 = (const float*)d_in[6];
  const float* s1b1 = (const float*)d_in[7];
  const float* s1w2 = (const float*)d_in[8];
  const float* s1b2 = (const float*)d_in[9];
  const float* s2w0 = (const float*)d_in[10];
  const float* s2b0 = (const float*)d_in[11];
  const float* s2w1 = (const float*)d_in[12];
  const float* s2b1 = (const float*)d_in[13];
  const float* s2w2 = (const float*)d_in[14];
  const float* s2b2 = (const float*)d_in[15];
  const float* s3w0 = (const float*)d_in[16];
  const float* s3b0 = (const float*)d_in[17];
  const float* s3w1 = (const float*)d_in[18];
  const float* s3b1 = (const float*)d_in[19];
  const float* s3w2 = (const float*)d_in[20];
  const float* s3b2 = (const float*)d_in[21];
  (void)in_sizes; (void)n_in; (void)out_size; (void)ws_size;

  char* ws = (char*)d_ws;
  size_t off = 0;
  auto alloc = [&](size_t nbytes) {
    void* p = ws + off;
    off = (off + nbytes + 255) & ~(size_t)255;
    return p;
  };
  float* x0 = (float*)alloc((size_t)B * N0 * 32 * 4);
  float* pos1 = (float*)alloc((size_t)B * 1024 * 3 * 4);
  int* nbr1 = (int*)alloc((size_t)B * 1024 * KNB * 4);
  int* cnt1 = (int*)alloc((size_t)B * 1024 * 4);
  float* x1 = (float*)alloc((size_t)B * 1024 * 64 * 4);
  float* pos2 = (float*)alloc((size_t)B * 256 * 3 * 4);
  int* nbr2 = (int*)alloc((size_t)B * 256 * KNB * 4);
  int* cnt2 = (int*)alloc((size_t)B * 256 * 4);
  float* x2 = (float*)alloc((size_t)B * 256 * 256 * 4);
  int* nbr3 = (int*)alloc((size_t)B * 64 * KNB * 4);
  int* cnt3 = (int*)alloc((size_t)B * 64 * 4);
  unsigned short* w0h = (unsigned short*)alloc((size_t)PK_T0 * 2);
  unsigned short* w0l = (unsigned short*)alloc((size_t)PK_T0 * 2);
  unsigned short* w1h = (unsigned short*)alloc((size_t)PK_T1 * 2);
  unsigned short* w1l = (unsigned short*)alloc((size_t)PK_T1 * 2);
  unsigned short* w2h = (unsigned short*)alloc((size_t)PK_T2 * 2);
  unsigned short* w2l = (unsigned short*)alloc((size_t)PK_T2 * 2);
  unsigned short* v0h = (unsigned short*)alloc((size_t)PK_U0 * 2);
  unsigned short* v0l = (unsigned short*)alloc((size_t)PK_U0 * 2);
  unsigned short* v1h = (unsigned short*)alloc((size_t)PK_U1 * 2);
  unsigned short* v1l = (unsigned short*)alloc((size_t)PK_U1 * 2);
  unsigned short* v2h = (unsigned short*)alloc((size_t)PK_U2 * 2);
  unsigned short* v2l = (unsigned short*)alloc((size_t)PK_U2 * 2);
  int* fl = (int*)alloc((size_t)FL_TOTAL * 4);

  float* xout = (float*)d_out;                 // (B,64,512)
  float* pos3 = xout + (size_t)B * 64 * 512;   // (B,64,3)

  const float r2a = (float)(0.05 * 0.05);
  const float r2b = (float)(0.3 * 0.3);
  const float r2c = (float)(0.5 * 0.5);

  hipMemsetAsync(fl, 0, (size_t)FL_TOTAL * 4, stream);
  mega_kernel<<<MG_TOTAL, 256, 0, stream>>>(
      fl, pos, pos1, pos2, pos3, feat, emb, pid, x0,
      s3w0, s3w1, s3w2, s2w0, s2w1, s2w2,
      w0h, w0l, w1h, w1l, w2h, w2l, v0h, v0l, v1h, v1l, v2h, v2l,
      r2a, r2b, r2c, nbr1, cnt1, nbr2, cnt2, nbr3, cnt3,
      s1w0, s1b0, s1w1, s1b1, s1w2, s1b2, x1, s2b0, s2b1, s2b2, x2);
  conv3_mfma<<<B * 64, 256, 0, stream>>>(x2, pos2, pos3, nbr3, cnt3,
                                         w0h, s3b0, w1h, s3b1, w2h, s3b2, xout);
}

// Round 13
// 1284.989 us; speedup vs baseline: 1.3574x; 1.3574x over previous
//
#include <hip/hip_runtime.h>

#define DEVI static __device__ __forceinline__

constexpr int B = 8;
constexpr int N0 = 4096;
constexpr int KNB = 64;

typedef float f32x2 __attribute__((ext_vector_type(2)));
typedef float f32x4 __attribute__((ext_vector_type(4)));
typedef short bf16x8 __attribute__((ext_vector_type(8)));

// d2 exactly as numpy: ((dx*dx + dy*dy) + dz*dz), no FMA contraction.
DEVI float dist2f(float ax, float ay, float az, float bx, float by, float bz) {
#pragma clang fp contract(off)
  float dx = ax - bx;
  float dy = ay - by;
  float dz = az - bz;
  return (dx * dx + dy * dy) + dz * dz;
}
DEVI f32x2 dist2v(f32x2 ax, f32x2 ay, f32x2 az, float bx, float by, float bz) {
#pragma clang fp contract(off)
  f32x2 dx = ax - bx;
  f32x2 dy = ay - by;
  f32x2 dz = az - bz;
  return (dx * dx + dy * dy) + dz * dz;
}

DEVI unsigned long long packMinKey(float v, int i) {
  return ((unsigned long long)__float_as_uint(v) << 32) | (unsigned int)i;
}

// ---- u64 max wave-64 reduction (DPP, VALU pipe); broadcast via readlane(63).
template <int CTRL, int RM>
DEVI unsigned long long dppMaxU64(unsigned long long k) {
  unsigned lo = (unsigned)k, hi = (unsigned)(k >> 32);
  unsigned mlo = (unsigned)__builtin_amdgcn_update_dpp((int)lo, (int)lo, CTRL, RM, 0xf, false);
  unsigned mhi = (unsigned)__builtin_amdgcn_update_dpp((int)hi, (int)hi, CTRL, RM, 0xf, false);
  unsigned long long o = ((unsigned long long)mhi << 32) | mlo;
  return (k > o) ? k : o;
}
DEVI unsigned long long waveReduceMaxU64(unsigned long long k) {
  k = dppMaxU64<0x111, 0xf>(k);  // row_shr:1
  k = dppMaxU64<0x112, 0xf>(k);  // row_shr:2
  k = dppMaxU64<0x114, 0xf>(k);  // row_shr:4
  k = dppMaxU64<0x118, 0xf>(k);  // row_shr:8
  k = dppMaxU64<0x142, 0xa>(k);  // row_bcast:15 -> rows 1,3
  k = dppMaxU64<0x143, 0xc>(k);  // row_bcast:31 -> rows 2,3
  unsigned lo = (unsigned)__builtin_amdgcn_readlane((int)(unsigned)k, 63);
  unsigned hi = (unsigned)__builtin_amdgcn_readlane((int)(unsigned)(k >> 32), 63);
  return ((unsigned long long)hi << 32) | lo;
}

// ---- bf16 split helpers (RNE) ----
DEVI unsigned short bfhi(float x) {
  unsigned u = __float_as_uint(x);
  return (unsigned short)((u + 0x7FFFu + ((u >> 16) & 1u)) >> 16);
}
DEVI float bf2f(unsigned short h) { return __uint_as_float(((unsigned)h) << 16); }
DEVI void mkfrag(const float* p, bf16x8& hi, bf16x8& lo) {
#pragma unroll
  for (int e = 0; e < 8; ++e) {
    float x = p[e];
    unsigned short h = bfhi(x);
    float r = x - bf2f(h);
    unsigned short l2 = bfhi(r);
    hi[e] = (short)h;
    lo[e] = (short)l2;
  }
}

// ================= device bodies ======

DEVI void x0_body(const int* __restrict__ feat, const float* __restrict__ emb,
                  const float* __restrict__ pid, float* __restrict__ x0buf,
                  int bx, int t) {
  int gid = bx * 256 + t;
  if (gid >= B * N0 * 32) return;
  int c = gid & 31;
  int bn = gid >> 5;
  int n = bn & (N0 - 1);
  int f = feat[bn];
  float v = emb[f * 32 + c];
  if (n < 1024) v += pid[n * 32 + c];
  x0buf[gid] = v;
}

// ---- weight packing into MFMA-B fragment order ----
// B-fragment: lane l holds col n = l&15, k = (l>>4)*8+e. Packed:
// elem = ((nt*KS+ks)*64+l)*8+e; k >= Kreal -> 0.
DEVI void pack_body(int gid, const float* __restrict__ W, int Kreal, int KS,
                    int N, unsigned short* __restrict__ hi,
                    unsigned short* __restrict__ lo) {
  int e = gid & 7;
  int l = (gid >> 3) & 63;
  int rest = gid >> 9;
  int ks = rest % KS;
  int nt = rest / KS;
  int n = nt * 16 + (l & 15);
  int k = ks * 32 + (l >> 4) * 8 + e;
  float val = (k < Kreal) ? W[(size_t)k * N + n] : 0.f;
  unsigned short h = bfhi(val);
  float r = val - bf2f(h);
  hi[gid] = h;
  lo[gid] = bfhi(r);
}

// ---- farthest point sampling (selection semantics == jnp.argmax) ----
// Single-phase u64 DPP reduce. For NW>1 the wave leader decodes ITS wave's
// winner and reads posl BEFORE the barrier (overlaps wave arrival), publishing
// (key, xyz); after the barrier lanes max-select over NW entries with cndmask
// -> no dependent LDS read on the serial path. Keys unique -> exact argmax.
// smem: posl[NPTS] float4 | ekey[2][NW] u64 | epos[2][NW] float4
template <int NPTS, int M, int BLK>
DEVI void fps_body(char* smem, const float* __restrict__ pos,
                   float* __restrict__ pos_out, int b, int t) {
  constexpr int EPT = NPTS / BLK;
  constexpr int EP2 = EPT / 2;
  constexpr int NW = BLK / 64;
  constexpr int NWc = NW < 2 ? 2 : NW;
  float4* posl = (float4*)smem;
  unsigned long long* ekey = (unsigned long long*)(smem + (size_t)NPTS * 16);
  float4* epos = (float4*)(smem + (size_t)NPTS * 16 + 2 * NWc * 8);
  const float* pb = pos + (size_t)b * NPTS * 3;
  f32x2 px[EP2], py[EP2], pz[EP2], d[EP2];
#pragma unroll
  for (int e = 0; e < EP2; ++e) {
    int i0 = t + (2 * e) * BLK;
    int i1 = t + (2 * e + 1) * BLK;
    float x0 = pb[i0 * 3 + 0], y0 = pb[i0 * 3 + 1], z0 = pb[i0 * 3 + 2];
    float x1 = pb[i1 * 3 + 0], y1 = pb[i1 * 3 + 1], z1 = pb[i1 * 3 + 2];
    px[e] = (f32x2){x0, x1};
    py[e] = (f32x2){y0, y1};
    pz[e] = (f32x2){z0, z1};
    posl[i0] = make_float4(x0, y0, z0, 0.f);
    posl[i1] = make_float4(x1, y1, z1, 0.f);
  }
  float sx = pb[0], sy = pb[1], sz = pb[2];
  if (t == 0) {
    pos_out[(size_t)(b * M) * 3 + 0] = sx;
    pos_out[(size_t)(b * M) * 3 + 1] = sy;
    pos_out[(size_t)(b * M) * 3 + 2] = sz;
  }
  f32x2 m2 = (f32x2){-1.f, -1.f};
#pragma unroll
  for (int e = 0; e < EP2; ++e) {
    d[e] = dist2v(px[e], py[e], pz[e], sx, sy, sz);
    m2.x = fmaxf(m2.x, d[e].x);
    m2.y = fmaxf(m2.y, d[e].y);
  }
  for (int it = 1; it < M; ++it) {
    const float lm = fmaxf(m2.x, m2.y);  // lane max (>=1 element matches)
    unsigned cand = 0xffffffffu;
#pragma unroll
    for (int e = 0; e < EP2; ++e) {
      unsigned c0 = (d[e].x == lm) ? (unsigned)(t + (2 * e) * BLK) : 0xffffffffu;
      unsigned c1 = (d[e].y == lm) ? (unsigned)(t + (2 * e + 1) * BLK) : 0xffffffffu;
      unsigned cc = c0 < c1 ? c0 : c1;
      cand = cand < cc ? cand : cc;
    }
    unsigned long long k =
        ((unsigned long long)__float_as_uint(lm) << 32) |
        (unsigned)(0x7fffffffu - cand);
    k = waveReduceMaxU64(k);
    float spx, spy, spz;
    if constexpr (NW > 1) {
      const int buf = (it & 1) * NW;
      if ((t & 63) == 0) {
        unsigned wsel = 0x7fffffffu - (unsigned)(k & 0xffffffffULL);
        float4 wp = posl[wsel];  // pre-barrier read: overlaps wave arrival
        ekey[buf + (t >> 6)] = k;
        epos[buf + (t >> 6)] = wp;
      }
      __syncthreads();  // double-buffered -> single barrier race-free
      unsigned long long kk = ekey[buf + 0];
      float4 sp4 = epos[buf + 0];
#pragma unroll
      for (int w = 1; w < NW; ++w) {
        unsigned long long o = ekey[buf + w];
        float4 op = epos[buf + w];
        bool g = o > kk;
        kk = g ? o : kk;
        sp4.x = g ? op.x : sp4.x;
        sp4.y = g ? op.y : sp4.y;
        sp4.z = g ? op.z : sp4.z;
      }
      spx = sp4.x; spy = sp4.y; spz = sp4.z;
    } else {
      unsigned sel = 0x7fffffffu - (unsigned)(k & 0xffffffffULL);
      float4 sp4 = posl[sel];  // LDS broadcast
      spx = sp4.x; spy = sp4.y; spz = sp4.z;
    }
    if (t == 0) {
      pos_out[(size_t)(b * M + it) * 3 + 0] = spx;
      pos_out[(size_t)(b * M + it) * 3 + 1] = spy;
      pos_out[(size_t)(b * M + it) * 3 + 2] = spz;
    }
    f32x2 mm = (f32x2){-1.f, -1.f};
#pragma unroll
    for (int e = 0; e < EP2; ++e) {
      f32x2 nd = dist2v(px[e], py[e], pz[e], spx, spy, spz);
      d[e].x = fminf(d[e].x, nd.x);
      d[e].y = fminf(d[e].y, nd.y);
      mm.x = fmaxf(mm.x, d[e].x);
      mm.y = fmaxf(mm.y, d[e].y);
    }
    m2 = mm;
  }
}

// ---- radius neighbors (<=64 nearest within r), rank-select overflow ----
template <int NPTS, int M>
DEVI void radius_body(char* smem, const float* __restrict__ pos,
                      const float* __restrict__ pos_s, float r2,
                      int* __restrict__ nbr, int* __restrict__ cnt, int blk,
                      int t) {
  unsigned long long* candkey = (unsigned long long*)smem;
  int* ctrp = (int*)(smem + (size_t)NPTS * 8);
  const int b = blk / M;
  const float* pb = pos + (size_t)b * NPTS * 3;
  const float cx = pos_s[(size_t)blk * 3 + 0];
  const float cy = pos_s[(size_t)blk * 3 + 1];
  const float cz = pos_s[(size_t)blk * 3 + 2];
  if (t == 0) *ctrp = 0;
  __syncthreads();
  for (int j = t; j < NPTS; j += 256) {
    float d2 = dist2f(pb[j * 3 + 0], pb[j * 3 + 1], pb[j * 3 + 2], cx, cy, cz);
    if (d2 <= r2) {
      int p = atomicAdd(ctrp, 1);
      candkey[p] = packMinKey(d2, j);
      if (p < KNB) nbr[(size_t)blk * KNB + p] = j;
    }
  }
  __syncthreads();
  const int c = *ctrp;
  if (c <= KNB) {
    if (t == 0) cnt[blk] = c;
    return;
  }
  for (int s = t; s < c; s += 256) {
    unsigned long long mykey = candkey[s];
    int rank = 0;
#pragma unroll 4
    for (int j = 0; j < c; ++j) {
      rank += (candkey[j] < mykey) ? 1 : 0;
    }
    if (rank < KNB)
      nbr[(size_t)blk * KNB + rank] = (int)(unsigned)(mykey & 0xffffffffULL);
  }
  if (t == 0) cnt[blk] = KNB;
}

// ---- stage 1 conv: 35 -> 64 -> 64 -> 64, max over nbrs (4 slots x 64ch) ----
DEVI void conv1_body(char* smem, const float* __restrict__ x0buf,
                     const float* __restrict__ pos,
                     const float* __restrict__ pos_s,
                     const int* __restrict__ nbr, const int* __restrict__ cntp,
                     const float* __restrict__ w0, const float* __restrict__ b0,
                     const float* __restrict__ w1, const float* __restrict__ b1,
                     const float* __restrict__ w2, const float* __restrict__ b2,
                     float* __restrict__ x1, int blk, int t) {
  float(*ins)[36] = (float(*)[36])smem;
  float(*hh)[65] = (float(*)[65])(smem + 576);
  float(*sred)[65] = (float(*)[65])(smem + 1616);
  const int slot = t >> 6;
  const int ch = t & 63;
  const int b = blk >> 10;
  const int c = cntp[blk];
  const float cx = pos_s[(size_t)blk * 3 + 0];
  const float cy = pos_s[(size_t)blk * 3 + 1];
  const float cz = pos_s[(size_t)blk * 3 + 2];
  float best = -__builtin_inff();
  for (int r0 = 0; r0 < c; r0 += 4) {
    const int r = r0 + slot;
    const bool act = r < c;
    const int j = nbr[(size_t)blk * KNB + (act ? r : 0)];
    if (ch < 32) {
      ins[slot][ch] = x0buf[((size_t)(b * N0) + j) * 32 + ch];
    } else if (ch < 35) {
      float pv = pos[((size_t)(b * N0) + j) * 3 + (ch - 32)];
      float cv = (ch == 32) ? cx : (ch == 33) ? cy : cz;
      ins[slot][ch] = pv - cv;
    }
    __syncthreads();
    float v = b0[ch];
#pragma unroll
    for (int i = 0; i < 35; ++i) v = fmaf(ins[slot][i], w0[i * 64 + ch], v);
    v = fmaxf(v, 0.f);
    hh[slot][ch] = v;
    __syncthreads();
    float v2 = b1[ch];
#pragma unroll
    for (int i = 0; i < 64; ++i) v2 = fmaf(hh[slot][i], w1[i * 64 + ch], v2);
    v2 = fmaxf(v2, 0.f);
    __syncthreads();
    hh[slot][ch] = v2;
    __syncthreads();
    float v3 = b2[ch];
#pragma unroll
    for (int i = 0; i < 64; ++i) v3 = fmaf(hh[slot][i], w2[i * 64 + ch], v3);
    if (act) best = fmaxf(best, v3);
    __syncthreads();
  }
  sred[slot][ch] = best;
  __syncthreads();
  if (t < 64) {
    float v = sred[0][t];
#pragma unroll
    for (int s = 1; s < 4; ++s) v = fmaxf(v, sred[s][t]);
    x1[(size_t)blk * 64 + t] = v;
  }
}

// ---- stage 2 conv via split-bf16 MFMA: 67 -> 128 -> 128 -> 256 ----
DEVI void conv2_mfma_body(char* smem, const float* __restrict__ x1,
                          const float* __restrict__ pos1,
                          const float* __restrict__ pos2,
                          const int* __restrict__ nbr,
                          const int* __restrict__ cntp,
                          const unsigned short* __restrict__ w0h,
                          const float* __restrict__ b0,
                          const unsigned short* __restrict__ w1h,
                          const float* __restrict__ b1,
                          const unsigned short* __restrict__ w2h,
                          const float* __restrict__ b2,
                          float* __restrict__ x2, int blk, int t) {
  float(*h1)[132] = (float(*)[132])smem;
  float(*h2)[132] = (float(*)[132])(smem + 33792);
  float* red = (float*)smem;  // alias h1 (dead after L2 reads)
  const int b = blk >> 8;
  const int c = cntp[blk];
  const int w = t >> 6;
  const int lane = t & 63;
  const int cb = lane & 15;
  const int kb = lane >> 4;
  const int mrow = w * 16 + cb;  // A-fragment row
  const int jrow = nbr[(size_t)blk * KNB + (mrow < c ? mrow : c - 1)];
  const float* xrow = x1 + ((size_t)(b * 1024) + jrow) * 64;
  const float cx = pos2[(size_t)blk * 3 + 0];
  const float cy = pos2[(size_t)blk * 3 + 1];
  const float cz = pos2[(size_t)blk * 3 + 2];

  f32x4 acc1[8];
#pragma unroll
  for (int nt = 0; nt < 8; ++nt) acc1[nt] = (f32x4){0.f, 0.f, 0.f, 0.f};
#pragma unroll
  for (int ks = 0; ks < 2; ++ks) {
    float xv[8];
    *(float4*)&xv[0] = *(const float4*)&xrow[ks * 32 + kb * 8];
    *(float4*)&xv[4] = *(const float4*)&xrow[ks * 32 + kb * 8 + 4];
    bf16x8 ahi, alo;
    mkfrag(xv, ahi, alo);
#pragma unroll
    for (int nt = 0; nt < 8; ++nt) {
      size_t off = ((size_t)(nt * 3 + ks) * 64 + lane) * 8;
      bf16x8 bhi = *(const bf16x8*)(w0h + off);
      acc1[nt] = __builtin_amdgcn_mfma_f32_16x16x32_bf16(ahi, bhi, acc1[nt], 0, 0, 0);
      acc1[nt] = __builtin_amdgcn_mfma_f32_16x16x32_bf16(alo, bhi, acc1[nt], 0, 0, 0);
    }
  }
  {  // ks=2: k=64..66 = pos-diff (kb==0, e<3); weights zero-padded past 67
    float xv[8] = {0.f, 0.f, 0.f, 0.f, 0.f, 0.f, 0.f, 0.f};
    if (kb == 0) {
      xv[0] = pos1[((size_t)(b * 1024) + jrow) * 3 + 0] - cx;
      xv[1] = pos1[((size_t)(b * 1024) + jrow) * 3 + 1] - cy;
      xv[2] = pos1[((size_t)(b * 1024) + jrow) * 3 + 2] - cz;
    }
    bf16x8 ahi, alo;
    mkfrag(xv, ahi, alo);
#pragma unroll
    for (int nt = 0; nt < 8; ++nt) {
      size_t off = ((size_t)(nt * 3 + 2) * 64 + lane) * 8;
      bf16x8 bhi = *(const bf16x8*)(w0h + off);
      acc1[nt] = __builtin_amdgcn_mfma_f32_16x16x32_bf16(ahi, bhi, acc1[nt], 0, 0, 0);
      acc1[nt] = __builtin_amdgcn_mfma_f32_16x16x32_bf16(alo, bhi, acc1[nt], 0, 0, 0);
    }
  }
  {
    const int mw = w * 16 + kb * 4;
#pragma unroll
    for (int nt = 0; nt < 8; ++nt) {
      float bias = b0[nt * 16 + cb];
#pragma unroll
      for (int r = 0; r < 4; ++r)
        h1[mw + r][nt * 16 + cb] = fmaxf(acc1[nt][r] + bias, 0.f);
    }
  }

  f32x4 acc2[8];
#pragma unroll
  for (int nt = 0; nt < 8; ++nt) acc2[nt] = (f32x4){0.f, 0.f, 0.f, 0.f};
#pragma unroll
  for (int ks = 0; ks < 4; ++ks) {
    bf16x8 ahi, alo;
    mkfrag(&h1[mrow][ks * 32 + kb * 8], ahi, alo);
#pragma unroll
    for (int nt = 0; nt < 8; ++nt) {
      size_t off = ((size_t)(nt * 4 + ks) * 64 + lane) * 8;
      bf16x8 bhi = *(const bf16x8*)(w1h + off);
      acc2[nt] = __builtin_amdgcn_mfma_f32_16x16x32_bf16(ahi, bhi, acc2[nt], 0, 0, 0);
      acc2[nt] = __builtin_amdgcn_mfma_f32_16x16x32_bf16(alo, bhi, acc2[nt], 0, 0, 0);
    }
  }
  {
    const int mw = w * 16 + kb * 4;
#pragma unroll
    for (int nt = 0; nt < 8; ++nt) {
      float bias = b1[nt * 16 + cb];
#pragma unroll
      for (int r = 0; r < 4; ++r)
        h2[mw + r][nt * 16 + cb] = fmaxf(acc2[nt][r] + bias, 0.f);
    }
  }

  f32x4 acc3[16];
#pragma unroll
  for (int nt = 0; nt < 16; ++nt) acc3[nt] = (f32x4){0.f, 0.f, 0.f, 0.f};
#pragma unroll
  for (int ks = 0; ks < 4; ++ks) {
    bf16x8 ahi, alo;
    mkfrag(&h2[mrow][ks * 32 + kb * 8], ahi, alo);
#pragma unroll
    for (int nt = 0; nt < 16; ++nt) {
      size_t off = ((size_t)(nt * 4 + ks) * 64 + lane) * 8;
      bf16x8 bhi = *(const bf16x8*)(w2h + off);
      acc3[nt] = __builtin_amdgcn_mfma_f32_16x16x32_bf16(ahi, bhi, acc3[nt], 0, 0, 0);
      acc3[nt] = __builtin_amdgcn_mfma_f32_16x16x32_bf16(alo, bhi, acc3[nt], 0, 0, 0);
    }
  }
  __syncthreads();  // all h1 reads done before red (aliases h1)
  {
    const int mw = w * 16 + kb * 4;
#pragma unroll
    for (int nt = 0; nt < 16; ++nt) {
      float bias = b2[nt * 16 + cb];
      float mx = -__builtin_inff();
#pragma unroll
      for (int r = 0; r < 4; ++r) {
        if (mw + r < c) mx = fmaxf(mx, acc3[nt][r] + bias);
      }
      red[(w * 4 + kb) * 256 + nt * 16 + cb] = mx;
    }
  }
  __syncthreads();
  {
    float v = red[t];
#pragma unroll
    for (int g = 1; g < 16; ++g) v = fmaxf(v, red[g * 256 + t]);
    x2[(size_t)blk * 256 + t] = v;
  }
}

// ================= merged launch kernels ====================================

constexpr int PK_T0 = 16 * 9 * 64 * 8;   // conv3 L1
constexpr int PK_T1 = 32 * 8 * 64 * 8;   // conv3 L2
constexpr int PK_T2 = 32 * 16 * 64 * 8;  // conv3 L3
constexpr int PK_U0 = 8 * 3 * 64 * 8;    // conv2 L1
constexpr int PK_U1 = 8 * 4 * 64 * 8;    // conv2 L2
constexpr int PK_U2 = 16 * 4 * 64 * 8;   // conv2 L3
constexpr int PK_TOTAL = PK_T0 + PK_T1 + PK_T2 + PK_U0 + PK_U1 + PK_U2;
constexpr int PK_BLOCKS = PK_TOTAL / 256;  // 2064

// L1: fps1 (0..7) || x0 (8..4103) || weight packing (4104..)
__global__ void __launch_bounds__(256) l1_kernel(
    const float* __restrict__ pos, float* __restrict__ pos1,
    const int* __restrict__ feat, const float* __restrict__ emb,
    const float* __restrict__ pid, float* __restrict__ x0buf,
    const float* __restrict__ s3w0, const float* __restrict__ s3w1,
    const float* __restrict__ s3w2, const float* __restrict__ s2w0,
    const float* __restrict__ s2w1, const float* __restrict__ s2w2,
    unsigned short* __restrict__ w0h, unsigned short* __restrict__ w0l,
    unsigned short* __restrict__ w1h, unsigned short* __restrict__ w1l,
    unsigned short* __restrict__ w2h, unsigned short* __restrict__ w2l,
    unsigned short* __restrict__ v0h, unsigned short* __restrict__ v0l,
    unsigned short* __restrict__ v1h, unsigned short* __restrict__ v1l,
    unsigned short* __restrict__ v2h, unsigned short* __restrict__ v2l) {
  __shared__ __attribute__((aligned(16))) char smem[65792];
  int bx = blockIdx.x;
  if (bx < 8) {
    fps_body<4096, 1024, 256>(smem, pos, pos1, bx, threadIdx.x);
    return;
  }
  bx -= 8;
  if (bx < 4096) {
    x0_body(feat, emb, pid, x0buf, bx, threadIdx.x);
    return;
  }
  bx -= 4096;
  int gid = bx * 256 + threadIdx.x;
  if (gid < PK_T0) { pack_body(gid, s3w0, 259, 9, 256, w0h, w0l); return; }
  gid -= PK_T0;
  if (gid < PK_T1) { pack_body(gid, s3w1, 256, 8, 512, w1h, w1l); return; }
  gid -= PK_T1;
  if (gid < PK_T2) { pack_body(gid, s3w2, 512, 16, 512, w2h, w2l); return; }
  gid -= PK_T2;
  if (gid < PK_U0) { pack_body(gid, s2w0, 67, 3, 128, v0h, v0l); return; }
  gid -= PK_U0;
  if (gid < PK_U1) { pack_body(gid, s2w1, 128, 4, 128, v1h, v1l); return; }
  gid -= PK_U1;
  if (gid < PK_U2) { pack_body(gid, s2w2, 128, 4, 256, v2h, v2l); return; }
}

// L2: fps2 single-wave (blocks 0..7) || radius1 (blocks 8..8199)
__global__ void __launch_bounds__(256) l2_kernel(
    const float* __restrict__ pos1, float* __restrict__ pos2,
    const float* __restrict__ pos, float r2a, int* __restrict__ nbr1,
    int* __restrict__ cnt1) {
  __shared__ __attribute__((aligned(16))) char smem[33024];
  if (blockIdx.x < 8) {
    if (threadIdx.x < 64)
      fps_body<1024, 256, 64>(smem, pos1, pos2, blockIdx.x, threadIdx.x);
  } else {
    radius_body<4096, 1024>(smem, pos, pos1, r2a, nbr1, cnt1, blockIdx.x - 8,
                            threadIdx.x);
  }
}

// L3: fps3 (blocks 0..7, wave0 only) || radius2 (8..2055) || conv1 (2056..10247)
__global__ void __launch_bounds__(256) l3_kernel(
    const float* __restrict__ pos2, float* __restrict__ pos3, float r2b,
    int* __restrict__ nbr2, int* __restrict__ cnt2,
    const float* __restrict__ pos1, const float* __restrict__ x0buf,
    const float* __restrict__ pos, const int* __restrict__ nbr1,
    const int* __restrict__ cnt1, const float* __restrict__ w0,
    const float* __restrict__ b0, const float* __restrict__ w1,
    const float* __restrict__ b1, const float* __restrict__ w2,
    const float* __restrict__ b2, float* __restrict__ x1) {
  __shared__ __attribute__((aligned(16))) char smem[8448];
  if (blockIdx.x < 8) {
    if (threadIdx.x < 64)
      fps_body<256, 64, 64>(smem, pos2, pos3, blockIdx.x, threadIdx.x);
  } else if (blockIdx.x < 8 + 2048) {
    radius_body<1024, 256>(smem, pos1, pos2, r2b, nbr2, cnt2, blockIdx.x - 8,
                           threadIdx.x);
  } else {
    conv1_body(smem, x0buf, pos, pos1, nbr1, cnt1, w0, b0, w1, b1, w2, b2, x1,
               blockIdx.x - (8 + 2048), threadIdx.x);
  }
}

// L4: radius3 (blocks 0..511) || conv2-MFMA (blocks 512..2559)
__global__ void __launch_bounds__(256) l4_kernel(
    const float* __restrict__ pos2, const float* __restrict__ pos3, float r2c,
    int* __restrict__ nbr3, int* __restrict__ cnt3,
    const float* __restrict__ x1, const float* __restrict__ pos1,
    const int* __restrict__ nbr2, const int* __restrict__ cnt2,
    const unsigned short* __restrict__ v0h, const float* __restrict__ b0,
    const unsigned short* __restrict__ v1h, const float* __restrict__ b1,
    const unsigned short* __restrict__ v2h, const float* __restrict__ b2,
    float* __restrict__ x2) {
  __shared__ __attribute__((aligned(16))) char smem[67584];
  if (blockIdx.x < 512) {
    radius_body<256, 64>(smem, pos2, pos3, r2c, nbr3, cnt3, blockIdx.x,
                         threadIdx.x);
  } else {
    conv2_mfma_body(smem, x1, pos1, pos2, nbr2, cnt2, v0h, b0, v1h, b1, v2h,
                    b2, x2, blockIdx.x - 512, threadIdx.x);
  }
}

// ---------------- stage 3 conv via split-bf16 MFMA (2-term, barrier-light) --
__global__ void __launch_bounds__(256) conv3_mfma(
    const float* __restrict__ x2, const float* __restrict__ pos2,
    const float* __restrict__ pos3, const int* __restrict__ nbr,
    const int* __restrict__ cntp,
    const unsigned short* __restrict__ w0h, const float* __restrict__ b0,
    const unsigned short* __restrict__ w1h, const float* __restrict__ b1,
    const unsigned short* __restrict__ w2h, const float* __restrict__ b2,
    float* __restrict__ out) {
  __shared__ __attribute__((aligned(16))) float h1s[64 * 268];
  __shared__ __attribute__((aligned(16))) float h2cs[64 * 140];
  const int blk = blockIdx.x;
  const int t = threadIdx.x;
  const int b = blk >> 6;
  const int c = cntp[blk];
  const int w = t >> 6;
  const int lane = t & 63;
  const int cb = lane & 15;
  const int kb = lane >> 4;
  const float cx = pos3[(size_t)blk * 3 + 0];
  const float cy = pos3[(size_t)blk * 3 + 1];
  const float cz = pos3[(size_t)blk * 3 + 2];
  const int mrow = w * 16 + cb;
  const int jrow = nbr[(size_t)blk * KNB + (mrow < c ? mrow : c - 1)];
  const float* xrow = x2 + ((size_t)(b * 256) + jrow) * 256;

  f32x4 acc1[16];
#pragma unroll
  for (int nt = 0; nt < 16; ++nt) acc1[nt] = (f32x4){0.f, 0.f, 0.f, 0.f};
#pragma unroll
  for (int ks = 0; ks < 8; ++ks) {
    float xv[8];
    *(float4*)&xv[0] = *(const float4*)&xrow[ks * 32 + kb * 8];
    *(float4*)&xv[4] = *(const float4*)&xrow[ks * 32 + kb * 8 + 4];
    bf16x8 ahi, alo;
    mkfrag(xv, ahi, alo);
#pragma unroll
    for (int nt = 0; nt < 16; ++nt) {
      size_t off = ((size_t)(nt * 9 + ks) * 64 + lane) * 8;
      bf16x8 bhi = *(const bf16x8*)(w0h + off);
      acc1[nt] = __builtin_amdgcn_mfma_f32_16x16x32_bf16(ahi, bhi, acc1[nt], 0, 0, 0);
      acc1[nt] = __builtin_amdgcn_mfma_f32_16x16x32_bf16(alo, bhi, acc1[nt], 0, 0, 0);
    }
  }
  {
    float xv[8] = {0.f, 0.f, 0.f, 0.f, 0.f, 0.f, 0.f, 0.f};
    if (kb == 0) {
      xv[0] = pos2[((size_t)(b * 256) + jrow) * 3 + 0] - cx;
      xv[1] = pos2[((size_t)(b * 256) + jrow) * 3 + 1] - cy;
      xv[2] = pos2[((size_t)(b * 256) + jrow) * 3 + 2] - cz;
    }
    bf16x8 ahi, alo;
    mkfrag(xv, ahi, alo);
#pragma unroll
    for (int nt = 0; nt < 16; ++nt) {
      size_t off = ((size_t)(nt * 9 + 8) * 64 + lane) * 8;
      bf16x8 bhi = *(const bf16x8*)(w0h + off);
      acc1[nt] = __builtin_amdgcn_mfma_f32_16x16x32_bf16(ahi, bhi, acc1[nt], 0, 0, 0);
      acc1[nt] = __builtin_amdgcn_mfma_f32_16x16x32_bf16(alo, bhi, acc1[nt], 0, 0, 0);
    }
  }
  {
    const int mw = w * 16 + kb * 4;
#pragma unroll
    for (int nt = 0; nt < 16; ++nt) {
      float bias = b0[nt * 16 + cb];
#pragma unroll
      for (int r = 0; r < 4; ++r)
        h1s[(mw + r) * 268 + nt * 16 + cb] = fmaxf(acc1[nt][r] + bias, 0.f);
    }
  }

  f32x4 acc3[32];
#pragma unroll
  for (int nt = 0; nt < 32; ++nt) acc3[nt] = (f32x4){0.f, 0.f, 0.f, 0.f};
  for (int ch = 0; ch < 4; ++ch) {
    f32x4 acc2[8];
#pragma unroll
    for (int nt = 0; nt < 8; ++nt) acc2[nt] = (f32x4){0.f, 0.f, 0.f, 0.f};
#pragma unroll
    for (int ks = 0; ks < 8; ++ks) {
      bf16x8 ahi, alo;
      mkfrag(&h1s[mrow * 268 + ks * 32 + kb * 8], ahi, alo);
#pragma unroll
      for (int nt = 0; nt < 8; ++nt) {
        size_t off = ((size_t)((ch * 8 + nt) * 8 + ks) * 64 + lane) * 8;
        bf16x8 bhi = *(const bf16x8*)(w1h + off);
        acc2[nt] = __builtin_amdgcn_mfma_f32_16x16x32_bf16(ahi, bhi, acc2[nt], 0, 0, 0);
        acc2[nt] = __builtin_amdgcn_mfma_f32_16x16x32_bf16(alo, bhi, acc2[nt], 0, 0, 0);
      }
    }
    {
      const int mw = w * 16 + kb * 4;
#pragma unroll
      for (int nt = 0; nt < 8; ++nt) {
        float bias = b1[ch * 128 + nt * 16 + cb];
#pragma unroll
        for (int r = 0; r < 4; ++r)
          h2cs[(mw + r) * 140 + nt * 16 + cb] = fmaxf(acc2[nt][r] + bias, 0.f);
      }
    }
#pragma unroll
    for (int ks3 = 0; ks3 < 4; ++ks3) {
      bf16x8 ahi, alo;
      mkfrag(&h2cs[mrow * 140 + ks3 * 32 + kb * 8], ahi, alo);
#pragma unroll
      for (int nt = 0; nt < 32; ++nt) {
        size_t off = ((size_t)(nt * 16 + ch * 4 + ks3) * 64 + lane) * 8;
        bf16x8 bhi = *(const bf16x8*)(w2h + off);
        acc3[nt] = __builtin_amdgcn_mfma_f32_16x16x32_bf16(ahi, bhi, acc3[nt], 0, 0, 0);
        acc3[nt] = __builtin_amdgcn_mfma_f32_16x16x32_bf16(alo, bhi, acc3[nt], 0, 0, 0);
      }
    }
  }

  __syncthreads();  // all h1s reads done before alias reuse
  float* redw = h1s;
  {
    const int mw = w * 16 + kb * 4;
#pragma unroll
    for (int nt = 0; nt < 32; ++nt) {
      float bias = b2[nt * 16 + cb];
      float mx = -__builtin_inff();
#pragma unroll
      for (int r = 0; r < 4; ++r) {
        if (mw + r < c) mx = fmaxf(mx, acc3[nt][r] + bias);
      }
      redw[(w * 4 + kb) * 512 + nt * 16 + cb] = mx;
    }
  }
  __syncthreads();
#pragma unroll
  for (int half = 0; half < 2; ++half) {
    int col = t + half * 256;
    float v = redw[col];
#pragma unroll
    for (int g = 1; g < 16; ++g) v = fmaxf(v, redw[g * 512 + col]);
    out[(size_t)blk * 512 + col] = v;
  }
}

extern "C" void kernel_launch(void* const* d_in, const int* in_sizes, int n_in,
                              void* d_out, int out_size, void* d_ws, size_t ws_size,
                              hipStream_t stream) {
  const int* feat = (const int*)d_in[0];
  const float* pos = (const float*)d_in[1];
  const float* emb = (const float*)d_in[2];
  const float* pid = (const float*)d_in[3];
  const float* s1w0 = (const float*)d_in[4];
  const float* s1b0 = (const float*)d_in[5];
  const float* s1w1 = (const float*)d_in[6];
  const float* s1b1 = (const float*)d_in[7];
  const float* s1w2 = (const float*)d_in[8];
  const float* s1b2 = (const float*)d_in[9];
  const float* s2w0 = (const float*)d_in[10];
  const float* s2b0 = (const float*)d_in[11];
  const float* s2w1 = (const float*)d_in[12];
  const float* s2b1 = (const float*)d_in[13];
  const float* s2w2 = (const float*)d_in[14];
  const float* s2b2 = (const float*)d_in[15];
  const float* s3w0 = (const float*)d_in[16];
  const float* s3b0 = (const float*)d_in[17];
  const float* s3w1 = (const float*)d_in[18];
  const float* s3b1 = (const float*)d_in[19];
  const float* s3w2 = (const float*)d_in[20];
  const float* s3b2 = (const float*)d_in[21];
  (void)in_sizes; (void)n_in; (void)out_size; (void)ws_size;

  char* ws = (char*)d_ws;
  size_t off = 0;
  auto alloc = [&](size_t nbytes) {
    void* p = ws + off;
    off = (off + nbytes + 255) & ~(size_t)255;
    return p;
  };
  float* x0 = (float*)alloc((size_t)B * N0 * 32 * 4);
  float* pos1 = (float*)alloc((size_t)B * 1024 * 3 * 4);
  int* nbr1 = (int*)alloc((size_t)B * 1024 * KNB * 4);
  int* cnt1 = (int*)alloc((size_t)B * 1024 * 4);
  float* x1 = (float*)alloc((size_t)B * 1024 * 64 * 4);
  float* pos2 = (float*)alloc((size_t)B * 256 * 3 * 4);
  int* nbr2 = (int*)alloc((size_t)B * 256 * KNB * 4);
  int* cnt2 = (int*)alloc((size_t)B * 256 * 4);
  float* x2 = (float*)alloc((size_t)B * 256 * 256 * 4);
  int* nbr3 = (int*)alloc((size_t)B * 64 * KNB * 4);
  int* cnt3 = (int*)alloc((size_t)B * 64 * 4);
  unsigned short* w0h = (unsigned short*)alloc((size_t)PK_T0 * 2);
  unsigned short* w0l = (unsigned short*)alloc((size_t)PK_T0 * 2);
  unsigned short* w1h = (unsigned short*)alloc((size_t)PK_T1 * 2);
  unsigned short* w1l = (unsigned short*)alloc((size_t)PK_T1 * 2);
  unsigned short* w2h = (unsigned short*)alloc((size_t)PK_T2 * 2);
  unsigned short* w2l = (unsigned short*)alloc((size_t)PK_T2 * 2);
  unsigned short* v0h = (unsigned short*)alloc((size_t)PK_U0 * 2);
  unsigned short* v0l = (unsigned short*)alloc((size_t)PK_U0 * 2);
  unsigned short* v1h = (unsigned short*)alloc((size_t)PK_U1 * 2);
  unsigned short* v1l = (unsigned short*)alloc((size_t)PK_U1 * 2);
  unsigned short* v2h = (unsigned short*)alloc((size_t)PK_U2 * 2);
  unsigned short* v2l = (unsigned short*)alloc((size_t)PK_U2 * 2);

  float* xout = (float*)d_out;                 // (B,64,512)
  float* pos3 = xout + (size_t)B * 64 * 512;   // (B,64,3)

  const float r2a = (float)(0.05 * 0.05);
  const float r2b = (float)(0.3 * 0.3);
  const float r2c = (float)(0.5 * 0.5);

  l1_kernel<<<8 + 4096 + PK_BLOCKS, 256, 0, stream>>>(
      pos, pos1, feat, emb, pid, x0, s3w0, s3w1, s3w2, s2w0, s2w1, s2w2,
      w0h, w0l, w1h, w1l, w2h, w2l, v0h, v0l, v1h, v1l, v2h, v2l);
  l2_kernel<<<8 + 8192, 256, 0, stream>>>(pos1, pos2, pos, r2a, nbr1, cnt1);
  l3_kernel<<<8 + 2048 + 8192, 256, 0, stream>>>(
      pos2, pos3, r2b, nbr2, cnt2, pos1, x0, pos, nbr1, cnt1,
      s1w0, s1b0, s1w1, s1b1, s1w2, s1b2, x1);
  l4_kernel<<<512 + 2048, 256, 0, stream>>>(
      pos2, pos3, r2c, nbr3, cnt3, x1, pos1, nbr2, cnt2,
      v0h, s2b0, v1h, s2b1, v2h, s2b2, x2);
  conv3_mfma<<<B * 64, 256, 0, stream>>>(x2, pos2, pos3, nbr3, cnt3,
                                         w0h, s3b0, w1h, s3b1, w2h, s3b2, xout);
}

// Round 14
// 1248.186 us; speedup vs baseline: 1.3974x; 1.0295x over previous
//
#include <hip/hip_runtime.h>

#define DEVI static __device__ __forceinline__

constexpr int B = 8;
constexpr int N0 = 4096;
constexpr int KNB = 64;

typedef float f32x2 __attribute__((ext_vector_type(2)));
typedef float f32x4 __attribute__((ext_vector_type(4)));
typedef short bf16x8 __attribute__((ext_vector_type(8)));

// d2 exactly as numpy: ((dx*dx + dy*dy) + dz*dz), no FMA contraction.
DEVI float dist2f(float ax, float ay, float az, float bx, float by, float bz) {
#pragma clang fp contract(off)
  float dx = ax - bx;
  float dy = ay - by;
  float dz = az - bz;
  return (dx * dx + dy * dy) + dz * dz;
}
DEVI f32x2 dist2v(f32x2 ax, f32x2 ay, f32x2 az, float bx, float by, float bz) {
#pragma clang fp contract(off)
  f32x2 dx = ax - bx;
  f32x2 dy = ay - by;
  f32x2 dz = az - bz;
  return (dx * dx + dy * dy) + dz * dz;
}

DEVI unsigned long long packMinKey(float v, int i) {
  return ((unsigned long long)__float_as_uint(v) << 32) | (unsigned int)i;
}

// ---- u64 max wave-64 reduction (DPP, VALU pipe); broadcast via readlane(63).
template <int CTRL, int RM>
DEVI unsigned long long dppMaxU64(unsigned long long k) {
  unsigned lo = (unsigned)k, hi = (unsigned)(k >> 32);
  unsigned mlo = (unsigned)__builtin_amdgcn_update_dpp((int)lo, (int)lo, CTRL, RM, 0xf, false);
  unsigned mhi = (unsigned)__builtin_amdgcn_update_dpp((int)hi, (int)hi, CTRL, RM, 0xf, false);
  unsigned long long o = ((unsigned long long)mhi << 32) | mlo;
  return (k > o) ? k : o;
}
DEVI unsigned long long waveReduceMaxU64(unsigned long long k) {
  k = dppMaxU64<0x111, 0xf>(k);  // row_shr:1
  k = dppMaxU64<0x112, 0xf>(k);  // row_shr:2
  k = dppMaxU64<0x114, 0xf>(k);  // row_shr:4
  k = dppMaxU64<0x118, 0xf>(k);  // row_shr:8
  k = dppMaxU64<0x142, 0xa>(k);  // row_bcast:15 -> rows 1,3
  k = dppMaxU64<0x143, 0xc>(k);  // row_bcast:31 -> rows 2,3
  unsigned lo = (unsigned)__builtin_amdgcn_readlane((int)(unsigned)k, 63);
  unsigned hi = (unsigned)__builtin_amdgcn_readlane((int)(unsigned)(k >> 32), 63);
  return ((unsigned long long)hi << 32) | lo;
}

// ---- bf16 split helpers (RNE) ----
DEVI unsigned short bfhi(float x) {
  unsigned u = __float_as_uint(x);
  return (unsigned short)((u + 0x7FFFu + ((u >> 16) & 1u)) >> 16);
}
DEVI float bf2f(unsigned short h) { return __uint_as_float(((unsigned)h) << 16); }
DEVI void mkfrag(const float* p, bf16x8& hi, bf16x8& lo) {
#pragma unroll
  for (int e = 0; e < 8; ++e) {
    float x = p[e];
    unsigned short h = bfhi(x);
    float r = x - bf2f(h);
    unsigned short l2 = bfhi(r);
    hi[e] = (short)h;
    lo[e] = (short)l2;
  }
}

// ================= device bodies ======

DEVI void x0_body(const int* __restrict__ feat, const float* __restrict__ emb,
                  const float* __restrict__ pid, float* __restrict__ x0buf,
                  int bx, int t) {
  int gid = bx * 256 + t;
  if (gid >= B * N0 * 32) return;
  int c = gid & 31;
  int bn = gid >> 5;
  int n = bn & (N0 - 1);
  int f = feat[bn];
  float v = emb[f * 32 + c];
  if (n < 1024) v += pid[n * 32 + c];
  x0buf[gid] = v;
}

// ---- weight packing into MFMA-B fragment order (body form) ----
// B-fragment: lane l holds col n = l&15, k = (l>>4)*8+e. Packed:
// elem = ((nt*KS+ks)*64+l)*8+e; k >= Kreal -> 0.
DEVI void pack_body(int gid, const float* __restrict__ W, int Kreal, int KS,
                    int N, unsigned short* __restrict__ hi,
                    unsigned short* __restrict__ lo) {
  int e = gid & 7;
  int l = (gid >> 3) & 63;
  int rest = gid >> 9;
  int ks = rest % KS;
  int nt = rest / KS;
  int n = nt * 16 + (l & 15);
  int k = ks * 32 + (l >> 4) * 8 + e;
  float val = (k < Kreal) ? W[(size_t)k * N + n] : 0.f;
  unsigned short h = bfhi(val);
  float r = val - bf2f(h);
  hi[gid] = h;
  lo[gid] = bfhi(r);
}

// ---- farthest point sampling (selection semantics == jnp.argmax) ----
// Single-phase: per-lane (lane-max, in-lane lowest idx) packed into one u64
// key (inverted idx low word: max key == max d2, ties -> lowest idx), one
// 6-level u64 DPP wave reduce; cross-wave via 1 leader-write + 1 barrier.
template <int NPTS, int M, int BLK>
DEVI void fps_body(char* smem, const float* __restrict__ pos,
                   float* __restrict__ pos_out, int b, int t) {
  constexpr int EPT = NPTS / BLK;
  constexpr int EP2 = EPT / 2;
  constexpr int NW = BLK / 64;
  float4* posl = (float4*)smem;
  float4* outp = (float4*)(smem + (size_t)NPTS * 16);
  unsigned long long* redk =
      (unsigned long long*)(smem + (size_t)(NPTS + M) * 16);  // [2][NW]
  const float* pb = pos + (size_t)b * NPTS * 3;
  f32x2 px[EP2], py[EP2], pz[EP2], d[EP2];
#pragma unroll
  for (int e = 0; e < EP2; ++e) {
    int i0 = t + (2 * e) * BLK;
    int i1 = t + (2 * e + 1) * BLK;
    float x0 = pb[i0 * 3 + 0], y0 = pb[i0 * 3 + 1], z0 = pb[i0 * 3 + 2];
    float x1 = pb[i1 * 3 + 0], y1 = pb[i1 * 3 + 1], z1 = pb[i1 * 3 + 2];
    px[e] = (f32x2){x0, x1};
    py[e] = (f32x2){y0, y1};
    pz[e] = (f32x2){z0, z1};
    posl[i0] = make_float4(x0, y0, z0, 0.f);
    posl[i1] = make_float4(x1, y1, z1, 0.f);
  }
  float sx = pb[0], sy = pb[1], sz = pb[2];
  if (t == 0) outp[0] = make_float4(sx, sy, sz, 0.f);
  f32x2 m2 = (f32x2){-1.f, -1.f};
#pragma unroll
  for (int e = 0; e < EP2; ++e) {
    d[e] = dist2v(px[e], py[e], pz[e], sx, sy, sz);
    m2.x = fmaxf(m2.x, d[e].x);
    m2.y = fmaxf(m2.y, d[e].y);
  }
  for (int it = 1; it < M; ++it) {
    const float lm = fmaxf(m2.x, m2.y);  // this lane's max (>=1 match below)
    // in-lane lowest index attaining lm (tree min)
    unsigned cand = 0xffffffffu;
#pragma unroll
    for (int e = 0; e < EP2; ++e) {
      unsigned c0 = (d[e].x == lm) ? (unsigned)(t + (2 * e) * BLK) : 0xffffffffu;
      unsigned c1 = (d[e].y == lm) ? (unsigned)(t + (2 * e + 1) * BLK) : 0xffffffffu;
      unsigned cc = c0 < c1 ? c0 : c1;
      cand = cand < cc ? cand : cc;
    }
    unsigned long long k =
        ((unsigned long long)__float_as_uint(lm) << 32) |
        (unsigned)(0x7fffffffu - cand);
    k = waveReduceMaxU64(k);
    unsigned sel;
    if constexpr (NW > 1) {
      if ((t & 63) == 0) redk[(it & 1) * NW + (t >> 6)] = k;
      __syncthreads();  // double-buffered -> single barrier is race-free
      unsigned long long kk = redk[(it & 1) * NW + 0];
#pragma unroll
      for (int w = 1; w < NW; ++w) {
        unsigned long long o = redk[(it & 1) * NW + w];
        kk = (kk > o) ? kk : o;
      }
      sel = 0x7fffffffu - (unsigned)(kk & 0xffffffffULL);
    } else {
      sel = 0x7fffffffu - (unsigned)(k & 0xffffffffULL);
    }
    float4 sp = posl[sel];  // LDS broadcast
    if (t == 0) outp[it] = sp;
    f32x2 mm = (f32x2){-1.f, -1.f};
#pragma unroll
    for (int e = 0; e < EP2; ++e) {
      f32x2 nd = dist2v(px[e], py[e], pz[e], sp.x, sp.y, sp.z);
      d[e].x = fminf(d[e].x, nd.x);
      d[e].y = fminf(d[e].y, nd.y);
      mm.x = fmaxf(mm.x, d[e].x);
      mm.y = fmaxf(mm.y, d[e].y);
    }
    m2 = mm;
  }
  if constexpr (NW > 1) __syncthreads();
  for (int m = t; m < M; m += BLK) {
    float4 q = outp[m];
    pos_out[(size_t)(b * M + m) * 3 + 0] = q.x;
    pos_out[(size_t)(b * M + m) * 3 + 1] = q.y;
    pos_out[(size_t)(b * M + m) * 3 + 2] = q.z;
  }
}

// ---- radius neighbors (<=64 nearest within r), rank-select overflow ----
template <int NPTS, int M>
DEVI void radius_body(char* smem, const float* __restrict__ pos,
                      const float* __restrict__ pos_s, float r2,
                      int* __restrict__ nbr, int* __restrict__ cnt, int blk,
                      int t) {
  unsigned long long* candkey = (unsigned long long*)smem;
  int* ctrp = (int*)(smem + (size_t)NPTS * 8);
  const int b = blk / M;
  const float* pb = pos + (size_t)b * NPTS * 3;
  const float cx = pos_s[(size_t)blk * 3 + 0];
  const float cy = pos_s[(size_t)blk * 3 + 1];
  const float cz = pos_s[(size_t)blk * 3 + 2];
  if (t == 0) *ctrp = 0;
  __syncthreads();
  for (int j = t; j < NPTS; j += 256) {
    float d2 = dist2f(pb[j * 3 + 0], pb[j * 3 + 1], pb[j * 3 + 2], cx, cy, cz);
    if (d2 <= r2) {
      int p = atomicAdd(ctrp, 1);
      candkey[p] = packMinKey(d2, j);
      if (p < KNB) nbr[(size_t)blk * KNB + p] = j;
    }
  }
  __syncthreads();
  const int c = *ctrp;
  if (c <= KNB) {
    if (t == 0) cnt[blk] = c;
    return;
  }
  for (int s = t; s < c; s += 256) {
    unsigned long long mykey = candkey[s];
    int rank = 0;
#pragma unroll 4
    for (int j = 0; j < c; ++j) {
      rank += (candkey[j] < mykey) ? 1 : 0;
    }
    if (rank < KNB)
      nbr[(size_t)blk * KNB + rank] = (int)(unsigned)(mykey & 0xffffffffULL);
  }
  if (t == 0) cnt[blk] = KNB;
}

// ---- stage 1 conv: 35 -> 64 -> 64 -> 64, max over nbrs (4 slots x 64ch) ----
DEVI void conv1_body(char* smem, const float* __restrict__ x0buf,
                     const float* __restrict__ pos,
                     const float* __restrict__ pos_s,
                     const int* __restrict__ nbr, const int* __restrict__ cntp,
                     const float* __restrict__ w0, const float* __restrict__ b0,
                     const float* __restrict__ w1, const float* __restrict__ b1,
                     const float* __restrict__ w2, const float* __restrict__ b2,
                     float* __restrict__ x1, int blk, int t) {
  float(*ins)[36] = (float(*)[36])smem;
  float(*hh)[65] = (float(*)[65])(smem + 576);
  float(*sred)[65] = (float(*)[65])(smem + 1616);
  const int slot = t >> 6;
  const int ch = t & 63;
  const int b = blk >> 10;
  const int c = cntp[blk];
  const float cx = pos_s[(size_t)blk * 3 + 0];
  const float cy = pos_s[(size_t)blk * 3 + 1];
  const float cz = pos_s[(size_t)blk * 3 + 2];
  float best = -__builtin_inff();
  for (int r0 = 0; r0 < c; r0 += 4) {
    const int r = r0 + slot;
    const bool act = r < c;
    const int j = nbr[(size_t)blk * KNB + (act ? r : 0)];
    if (ch < 32) {
      ins[slot][ch] = x0buf[((size_t)(b * N0) + j) * 32 + ch];
    } else if (ch < 35) {
      float pv = pos[((size_t)(b * N0) + j) * 3 + (ch - 32)];
      float cv = (ch == 32) ? cx : (ch == 33) ? cy : cz;
      ins[slot][ch] = pv - cv;
    }
    __syncthreads();
    float v = b0[ch];
#pragma unroll
    for (int i = 0; i < 35; ++i) v = fmaf(ins[slot][i], w0[i * 64 + ch], v);
    v = fmaxf(v, 0.f);
    hh[slot][ch] = v;
    __syncthreads();
    float v2 = b1[ch];
#pragma unroll
    for (int i = 0; i < 64; ++i) v2 = fmaf(hh[slot][i], w1[i * 64 + ch], v2);
    v2 = fmaxf(v2, 0.f);
    __syncthreads();
    hh[slot][ch] = v2;
    __syncthreads();
    float v3 = b2[ch];
#pragma unroll
    for (int i = 0; i < 64; ++i) v3 = fmaf(hh[slot][i], w2[i * 64 + ch], v3);
    if (act) best = fmaxf(best, v3);
    __syncthreads();
  }
  sred[slot][ch] = best;
  __syncthreads();
  if (t < 64) {
    float v = sred[0][t];
#pragma unroll
    for (int s = 1; s < 4; ++s) v = fmaxf(v, sred[s][t]);
    x1[(size_t)blk * 64 + t] = v;
  }
}

// ---- stage 2 conv via split-bf16 MFMA: 67 -> 128 -> 128 -> 256 ----
DEVI void conv2_mfma_body(char* smem, const float* __restrict__ x1,
                          const float* __restrict__ pos1,
                          const float* __restrict__ pos2,
                          const int* __restrict__ nbr,
                          const int* __restrict__ cntp,
                          const unsigned short* __restrict__ w0h,
                          const float* __restrict__ b0,
                          const unsigned short* __restrict__ w1h,
                          const float* __restrict__ b1,
                          const unsigned short* __restrict__ w2h,
                          const float* __restrict__ b2,
                          float* __restrict__ x2, int blk, int t) {
  float(*h1)[132] = (float(*)[132])smem;
  float(*h2)[132] = (float(*)[132])(smem + 33792);
  float* red = (float*)smem;  // alias h1 (dead after L2 reads)
  const int b = blk >> 8;
  const int c = cntp[blk];
  const int w = t >> 6;
  const int lane = t & 63;
  const int cb = lane & 15;
  const int kb = lane >> 4;
  const int mrow = w * 16 + cb;  // A-fragment row
  const int jrow = nbr[(size_t)blk * KNB + (mrow < c ? mrow : c - 1)];
  const float* xrow = x1 + ((size_t)(b * 1024) + jrow) * 64;
  const float cx = pos2[(size_t)blk * 3 + 0];
  const float cy = pos2[(size_t)blk * 3 + 1];
  const float cz = pos2[(size_t)blk * 3 + 2];

  f32x4 acc1[8];
#pragma unroll
  for (int nt = 0; nt < 8; ++nt) acc1[nt] = (f32x4){0.f, 0.f, 0.f, 0.f};
#pragma unroll
  for (int ks = 0; ks < 2; ++ks) {
    float xv[8];
    *(float4*)&xv[0] = *(const float4*)&xrow[ks * 32 + kb * 8];
    *(float4*)&xv[4] = *(const float4*)&xrow[ks * 32 + kb * 8 + 4];
    bf16x8 ahi, alo;
    mkfrag(xv, ahi, alo);
#pragma unroll
    for (int nt = 0; nt < 8; ++nt) {
      size_t off = ((size_t)(nt * 3 + ks) * 64 + lane) * 8;
      bf16x8 bhi = *(const bf16x8*)(w0h + off);
      acc1[nt] = __builtin_amdgcn_mfma_f32_16x16x32_bf16(ahi, bhi, acc1[nt], 0, 0, 0);
      acc1[nt] = __builtin_amdgcn_mfma_f32_16x16x32_bf16(alo, bhi, acc1[nt], 0, 0, 0);
    }
  }
  {  // ks=2: k=64..66 = pos-diff (kb==0, e<3); weights zero-padded past 67
    float xv[8] = {0.f, 0.f, 0.f, 0.f, 0.f, 0.f, 0.f, 0.f};
    if (kb == 0) {
      xv[0] = pos1[((size_t)(b * 1024) + jrow) * 3 + 0] - cx;
      xv[1] = pos1[((size_t)(b * 1024) + jrow) * 3 + 1] - cy;
      xv[2] = pos1[((size_t)(b * 1024) + jrow) * 3 + 2] - cz;
    }
    bf16x8 ahi, alo;
    mkfrag(xv, ahi, alo);
#pragma unroll
    for (int nt = 0; nt < 8; ++nt) {
      size_t off = ((size_t)(nt * 3 + 2) * 64 + lane) * 8;
      bf16x8 bhi = *(const bf16x8*)(w0h + off);
      acc1[nt] = __builtin_amdgcn_mfma_f32_16x16x32_bf16(ahi, bhi, acc1[nt], 0, 0, 0);
      acc1[nt] = __builtin_amdgcn_mfma_f32_16x16x32_bf16(alo, bhi, acc1[nt], 0, 0, 0);
    }
  }
  {
    const int mw = w * 16 + kb * 4;
#pragma unroll
    for (int nt = 0; nt < 8; ++nt) {
      float bias = b0[nt * 16 + cb];
#pragma unroll
      for (int r = 0; r < 4; ++r)
        h1[mw + r][nt * 16 + cb] = fmaxf(acc1[nt][r] + bias, 0.f);
    }
  }

  f32x4 acc2[8];
#pragma unroll
  for (int nt = 0; nt < 8; ++nt) acc2[nt] = (f32x4){0.f, 0.f, 0.f, 0.f};
#pragma unroll
  for (int ks = 0; ks < 4; ++ks) {
    bf16x8 ahi, alo;
    mkfrag(&h1[mrow][ks * 32 + kb * 8], ahi, alo);
#pragma unroll
    for (int nt = 0; nt < 8; ++nt) {
      size_t off = ((size_t)(nt * 4 + ks) * 64 + lane) * 8;
      bf16x8 bhi = *(const bf16x8*)(w1h + off);
      acc2[nt] = __builtin_amdgcn_mfma_f32_16x16x32_bf16(ahi, bhi, acc2[nt], 0, 0, 0);
      acc2[nt] = __builtin_amdgcn_mfma_f32_16x16x32_bf16(alo, bhi, acc2[nt], 0, 0, 0);
    }
  }
  {
    const int mw = w * 16 + kb * 4;
#pragma unroll
    for (int nt = 0; nt < 8; ++nt) {
      float bias = b1[nt * 16 + cb];
#pragma unroll
      for (int r = 0; r < 4; ++r)
        h2[mw + r][nt * 16 + cb] = fmaxf(acc2[nt][r] + bias, 0.f);
    }
  }

  f32x4 acc3[16];
#pragma unroll
  for (int nt = 0; nt < 16; ++nt) acc3[nt] = (f32x4){0.f, 0.f, 0.f, 0.f};
#pragma unroll
  for (int ks = 0; ks < 4; ++ks) {
    bf16x8 ahi, alo;
    mkfrag(&h2[mrow][ks * 32 + kb * 8], ahi, alo);
#pragma unroll
    for (int nt = 0; nt < 16; ++nt) {
      size_t off = ((size_t)(nt * 4 + ks) * 64 + lane) * 8;
      bf16x8 bhi = *(const bf16x8*)(w2h + off);
      acc3[nt] = __builtin_amdgcn_mfma_f32_16x16x32_bf16(ahi, bhi, acc3[nt], 0, 0, 0);
      acc3[nt] = __builtin_amdgcn_mfma_f32_16x16x32_bf16(alo, bhi, acc3[nt], 0, 0, 0);
    }
  }
  __syncthreads();  // all h1 reads done before red (aliases h1)
  {
    const int mw = w * 16 + kb * 4;
#pragma unroll
    for (int nt = 0; nt < 16; ++nt) {
      float bias = b2[nt * 16 + cb];
      float mx = -__builtin_inff();
#pragma unroll
      for (int r = 0; r < 4; ++r) {
        if (mw + r < c) mx = fmaxf(mx, acc3[nt][r] + bias);
      }
      red[(w * 4 + kb) * 256 + nt * 16 + cb] = mx;
    }
  }
  __syncthreads();
  {
    float v = red[t];
#pragma unroll
    for (int g = 1; g < 16; ++g) v = fmaxf(v, red[g * 256 + t]);
    x2[(size_t)blk * 256 + t] = v;
  }
}

// ================= merged launch kernels ====================================

constexpr int PK_T0 = 16 * 9 * 64 * 8;   // conv3 L1
constexpr int PK_T1 = 32 * 8 * 64 * 8;   // conv3 L2
constexpr int PK_T2 = 32 * 16 * 64 * 8;  // conv3 L3
constexpr int PK_U0 = 8 * 3 * 64 * 8;    // conv2 L1
constexpr int PK_U1 = 8 * 4 * 64 * 8;    // conv2 L2
constexpr int PK_U2 = 16 * 4 * 64 * 8;   // conv2 L3
constexpr int PK_TOTAL = PK_T0 + PK_T1 + PK_T2 + PK_U0 + PK_U1 + PK_U2;  // 528384
constexpr int PK_BLOCKS = PK_TOTAL / 256;  // 2064

// L1: fps1 (0..7) || x0 (8..4103) || weight packing (4104..4104+2064)
__global__ void __launch_bounds__(256) l1_kernel(
    const float* __restrict__ pos, float* __restrict__ pos1,
    const int* __restrict__ feat, const float* __restrict__ emb,
    const float* __restrict__ pid, float* __restrict__ x0buf,
    const float* __restrict__ s3w0, const float* __restrict__ s3w1,
    const float* __restrict__ s3w2, const float* __restrict__ s2w0,
    const float* __restrict__ s2w1, const float* __restrict__ s2w2,
    unsigned short* __restrict__ w0h, unsigned short* __restrict__ w0l,
    unsigned short* __restrict__ w1h, unsigned short* __restrict__ w1l,
    unsigned short* __restrict__ w2h, unsigned short* __restrict__ w2l,
    unsigned short* __restrict__ v0h, unsigned short* __restrict__ v0l,
    unsigned short* __restrict__ v1h, unsigned short* __restrict__ v1l,
    unsigned short* __restrict__ v2h, unsigned short* __restrict__ v2l) {
  __shared__ __attribute__((aligned(16))) char smem[81984];
  int bx = blockIdx.x;
  if (bx < 8) {
    fps_body<4096, 1024, 256>(smem, pos, pos1, bx, threadIdx.x);
    return;
  }
  bx -= 8;
  if (bx < 4096) {
    x0_body(feat, emb, pid, x0buf, bx, threadIdx.x);
    return;
  }
  bx -= 4096;
  int gid = bx * 256 + threadIdx.x;
  if (gid < PK_T0) { pack_body(gid, s3w0, 259, 9, 256, w0h, w0l); return; }
  gid -= PK_T0;
  if (gid < PK_T1) { pack_body(gid, s3w1, 256, 8, 512, w1h, w1l); return; }
  gid -= PK_T1;
  if (gid < PK_T2) { pack_body(gid, s3w2, 512, 16, 512, w2h, w2l); return; }
  gid -= PK_T2;
  if (gid < PK_U0) { pack_body(gid, s2w0, 67, 3, 128, v0h, v0l); return; }
  gid -= PK_U0;
  if (gid < PK_U1) { pack_body(gid, s2w1, 128, 4, 128, v1h, v1l); return; }
  gid -= PK_U1;
  if (gid < PK_U2) { pack_body(gid, s2w2, 128, 4, 256, v2h, v2l); return; }
}

// L2: fps2 single-wave (blocks 0..7) || radius1 (blocks 8..8199)
__global__ void __launch_bounds__(256) l2_kernel(
    const float* __restrict__ pos1, float* __restrict__ pos2,
    const float* __restrict__ pos, float r2a, int* __restrict__ nbr1,
    int* __restrict__ cnt1) {
  __shared__ __attribute__((aligned(16))) char smem[33024];
  if (blockIdx.x < 8) {
    if (threadIdx.x < 64)
      fps_body<1024, 256, 64>(smem, pos1, pos2, blockIdx.x, threadIdx.x);
  } else {
    radius_body<4096, 1024>(smem, pos, pos1, r2a, nbr1, cnt1, blockIdx.x - 8,
                            threadIdx.x);
  }
}

// L3: fps3 (blocks 0..7, wave0 only) || radius2 (8..2055) || conv1 (2056..10247)
__global__ void __launch_bounds__(256) l3_kernel(
    const float* __restrict__ pos2, float* __restrict__ pos3, float r2b,
    int* __restrict__ nbr2, int* __restrict__ cnt2,
    const float* __restrict__ pos1, const float* __restrict__ x0buf,
    const float* __restrict__ pos, const int* __restrict__ nbr1,
    const int* __restrict__ cnt1, const float* __restrict__ w0,
    const float* __restrict__ b0, const float* __restrict__ w1,
    const float* __restrict__ b1, const float* __restrict__ w2,
    const float* __restrict__ b2, float* __restrict__ x1) {
  __shared__ __attribute__((aligned(16))) char smem[8448];
  if (blockIdx.x < 8) {
    if (threadIdx.x < 64)
      fps_body<256, 64, 64>(smem, pos2, pos3, blockIdx.x, threadIdx.x);
  } else if (blockIdx.x < 8 + 2048) {
    radius_body<1024, 256>(smem, pos1, pos2, r2b, nbr2, cnt2, blockIdx.x - 8,
                           threadIdx.x);
  } else {
    conv1_body(smem, x0buf, pos, pos1, nbr1, cnt1, w0, b0, w1, b1, w2, b2, x1,
               blockIdx.x - (8 + 2048), threadIdx.x);
  }
}

// L4: radius3 (blocks 0..511) || conv2-MFMA (blocks 512..2559)
__global__ void __launch_bounds__(256) l4_kernel(
    const float* __restrict__ pos2, const float* __restrict__ pos3, float r2c,
    int* __restrict__ nbr3, int* __restrict__ cnt3,
    const float* __restrict__ x1, const float* __restrict__ pos1,
    const int* __restrict__ nbr2, const int* __restrict__ cnt2,
    const unsigned short* __restrict__ v0h, const float* __restrict__ b0,
    const unsigned short* __restrict__ v1h, const float* __restrict__ b1,
    const unsigned short* __restrict__ v2h, const float* __restrict__ b2,
    float* __restrict__ x2) {
  __shared__ __attribute__((aligned(16))) char smem[67584];
  if (blockIdx.x < 512) {
    radius_body<256, 64>(smem, pos2, pos3, r2c, nbr3, cnt3, blockIdx.x,
                         threadIdx.x);
  } else {
    conv2_mfma_body(smem, x1, pos1, pos2, nbr2, cnt2, v0h, b0, v1h, b1, v2h,
                    b2, x2, blockIdx.x - 512, threadIdx.x);
  }
}

// ---------------- stage 3 conv via split-bf16 MFMA (2-term, barrier-light) --
__global__ void __launch_bounds__(256) conv3_mfma(
    const float* __restrict__ x2, const float* __restrict__ pos2,
    const float* __restrict__ pos3, const int* __restrict__ nbr,
    const int* __restrict__ cntp,
    const unsigned short* __restrict__ w0h, const float* __restrict__ b0,
    const unsigned short* __restrict__ w1h, const float* __restrict__ b1,
    const unsigned short* __restrict__ w2h, const float* __restrict__ b2,
    float* __restrict__ out) {
  __shared__ __attribute__((aligned(16))) float h1s[64 * 268];
  __shared__ __attribute__((aligned(16))) float h2cs[64 * 140];
  const int blk = blockIdx.x;
  const int t = threadIdx.x;
  const int b = blk >> 6;
  const int c = cntp[blk];
  const int w = t >> 6;
  const int lane = t & 63;
  const int cb = lane & 15;
  const int kb = lane >> 4;
  const float cx = pos3[(size_t)blk * 3 + 0];
  const float cy = pos3[(size_t)blk * 3 + 1];
  const float cz = pos3[(size_t)blk * 3 + 2];
  const int mrow = w * 16 + cb;
  const int jrow = nbr[(size_t)blk * KNB + (mrow < c ? mrow : c - 1)];
  const float* xrow = x2 + ((size_t)(b * 256) + jrow) * 256;

  f32x4 acc1[16];
#pragma unroll
  for (int nt = 0; nt < 16; ++nt) acc1[nt] = (f32x4){0.f, 0.f, 0.f, 0.f};
#pragma unroll
  for (int ks = 0; ks < 8; ++ks) {
    float xv[8];
    *(float4*)&xv[0] = *(const float4*)&xrow[ks * 32 + kb * 8];
    *(float4*)&xv[4] = *(const float4*)&xrow[ks * 32 + kb * 8 + 4];
    bf16x8 ahi, alo;
    mkfrag(xv, ahi, alo);
#pragma unroll
    for (int nt = 0; nt < 16; ++nt) {
      size_t off = ((size_t)(nt * 9 + ks) * 64 + lane) * 8;
      bf16x8 bhi = *(const bf16x8*)(w0h + off);
      acc1[nt] = __builtin_amdgcn_mfma_f32_16x16x32_bf16(ahi, bhi, acc1[nt], 0, 0, 0);
      acc1[nt] = __builtin_amdgcn_mfma_f32_16x16x32_bf16(alo, bhi, acc1[nt], 0, 0, 0);
    }
  }
  {
    float xv[8] = {0.f, 0.f, 0.f, 0.f, 0.f, 0.f, 0.f, 0.f};
    if (kb == 0) {
      xv[0] = pos2[((size_t)(b * 256) + jrow) * 3 + 0] - cx;
      xv[1] = pos2[((size_t)(b * 256) + jrow) * 3 + 1] - cy;
      xv[2] = pos2[((size_t)(b * 256) + jrow) * 3 + 2] - cz;
    }
    bf16x8 ahi, alo;
    mkfrag(xv, ahi, alo);
#pragma unroll
    for (int nt = 0; nt < 16; ++nt) {
      size_t off = ((size_t)(nt * 9 + 8) * 64 + lane) * 8;
      bf16x8 bhi = *(const bf16x8*)(w0h + off);
      acc1[nt] = __builtin_amdgcn_mfma_f32_16x16x32_bf16(ahi, bhi, acc1[nt], 0, 0, 0);
      acc1[nt] = __builtin_amdgcn_mfma_f32_16x16x32_bf16(alo, bhi, acc1[nt], 0, 0, 0);
    }
  }
  {
    const int mw = w * 16 + kb * 4;
#pragma unroll
    for (int nt = 0; nt < 16; ++nt) {
      float bias = b0[nt * 16 + cb];
#pragma unroll
      for (int r = 0; r < 4; ++r)
        h1s[(mw + r) * 268 + nt * 16 + cb] = fmaxf(acc1[nt][r] + bias, 0.f);
    }
  }

  f32x4 acc3[32];
#pragma unroll
  for (int nt = 0; nt < 32; ++nt) acc3[nt] = (f32x4){0.f, 0.f, 0.f, 0.f};
  for (int ch = 0; ch < 4; ++ch) {
    f32x4 acc2[8];
#pragma unroll
    for (int nt = 0; nt < 8; ++nt) acc2[nt] = (f32x4){0.f, 0.f, 0.f, 0.f};
#pragma unroll
    for (int ks = 0; ks < 8; ++ks) {
      bf16x8 ahi, alo;
      mkfrag(&h1s[mrow * 268 + ks * 32 + kb * 8], ahi, alo);
#pragma unroll
      for (int nt = 0; nt < 8; ++nt) {
        size_t off = ((size_t)((ch * 8 + nt) * 8 + ks) * 64 + lane) * 8;
        bf16x8 bhi = *(const bf16x8*)(w1h + off);
        acc2[nt] = __builtin_amdgcn_mfma_f32_16x16x32_bf16(ahi, bhi, acc2[nt], 0, 0, 0);
        acc2[nt] = __builtin_amdgcn_mfma_f32_16x16x32_bf16(alo, bhi, acc2[nt], 0, 0, 0);
      }
    }
    {
      const int mw = w * 16 + kb * 4;
#pragma unroll
      for (int nt = 0; nt < 8; ++nt) {
        float bias = b1[ch * 128 + nt * 16 + cb];
#pragma unroll
        for (int r = 0; r < 4; ++r)
          h2cs[(mw + r) * 140 + nt * 16 + cb] = fmaxf(acc2[nt][r] + bias, 0.f);
      }
    }
#pragma unroll
    for (int ks3 = 0; ks3 < 4; ++ks3) {
      bf16x8 ahi, alo;
      mkfrag(&h2cs[mrow * 140 + ks3 * 32 + kb * 8], ahi, alo);
#pragma unroll
      for (int nt = 0; nt < 32; ++nt) {
        size_t off = ((size_t)(nt * 16 + ch * 4 + ks3) * 64 + lane) * 8;
        bf16x8 bhi = *(const bf16x8*)(w2h + off);
        acc3[nt] = __builtin_amdgcn_mfma_f32_16x16x32_bf16(ahi, bhi, acc3[nt], 0, 0, 0);
        acc3[nt] = __builtin_amdgcn_mfma_f32_16x16x32_bf16(alo, bhi, acc3[nt], 0, 0, 0);
      }
    }
  }

  __syncthreads();  // all h1s reads done before alias reuse
  float* redw = h1s;
  {
    const int mw = w * 16 + kb * 4;
#pragma unroll
    for (int nt = 0; nt < 32; ++nt) {
      float bias = b2[nt * 16 + cb];
      float mx = -__builtin_inff();
#pragma unroll
      for (int r = 0; r < 4; ++r) {
        if (mw + r < c) mx = fmaxf(mx, acc3[nt][r] + bias);
      }
      redw[(w * 4 + kb) * 512 + nt * 16 + cb] = mx;
    }
  }
  __syncthreads();
#pragma unroll
  for (int half = 0; half < 2; ++half) {
    int col = t + half * 256;
    float v = redw[col];
#pragma unroll
    for (int g = 1; g < 16; ++g) v = fmaxf(v, redw[g * 512 + col]);
    out[(size_t)blk * 512 + col] = v;
  }
}

extern "C" void kernel_launch(void* const* d_in, const int* in_sizes, int n_in,
                              void* d_out, int out_size, void* d_ws, size_t ws_size,
                              hipStream_t stream) {
  const int* feat = (const int*)d_in[0];
  const float* pos = (const float*)d_in[1];
  const float* emb = (const float*)d_in[2];
  const float* pid = (const float*)d_in[3];
  const float* s1w0 = (const float*)d_in[4];
  const float* s1b0 = (const float*)d_in[5];
  const float* s1w1 = (const float*)d_in[6];
  const float* s1b1 = (const float*)d_in[7];
  const float* s1w2 = (const float*)d_in[8];
  const float* s1b2 = (const float*)d_in[9];
  const float* s2w0 = (const float*)d_in[10];
  const float* s2b0 = (const float*)d_in[11];
  const float* s2w1 = (const float*)d_in[12];
  const float* s2b1 = (const float*)d_in[13];
  const float* s2w2 = (const float*)d_in[14];
  const float* s2b2 = (const float*)d_in[15];
  const float* s3w0 = (const float*)d_in[16];
  const float* s3b0 = (const float*)d_in[17];
  const float* s3w1 = (const float*)d_in[18];
  const float* s3b1 = (const float*)d_in[19];
  const float* s3w2 = (const float*)d_in[20];
  const float* s3b2 = (const float*)d_in[21];
  (void)in_sizes; (void)n_in; (void)out_size; (void)ws_size;

  char* ws = (char*)d_ws;
  size_t off = 0;
  auto alloc = [&](size_t nbytes) {
    void* p = ws + off;
    off = (off + nbytes + 255) & ~(size_t)255;
    return p;
  };
  float* x0 = (float*)alloc((size_t)B * N0 * 32 * 4);
  float* pos1 = (float*)alloc((size_t)B * 1024 * 3 * 4);
  int* nbr1 = (int*)alloc((size_t)B * 1024 * KNB * 4);
  int* cnt1 = (int*)alloc((size_t)B * 1024 * 4);
  float* x1 = (float*)alloc((size_t)B * 1024 * 64 * 4);
  float* pos2 = (float*)alloc((size_t)B * 256 * 3 * 4);
  int* nbr2 = (int*)alloc((size_t)B * 256 * KNB * 4);
  int* cnt2 = (int*)alloc((size_t)B * 256 * 4);
  float* x2 = (float*)alloc((size_t)B * 256 * 256 * 4);
  int* nbr3 = (int*)alloc((size_t)B * 64 * KNB * 4);
  int* cnt3 = (int*)alloc((size_t)B * 64 * 4);
  unsigned short* w0h = (unsigned short*)alloc((size_t)PK_T0 * 2);
  unsigned short* w0l = (unsigned short*)alloc((size_t)PK_T0 * 2);
  unsigned short* w1h = (unsigned short*)alloc((size_t)PK_T1 * 2);
  unsigned short* w1l = (unsigned short*)alloc((size_t)PK_T1 * 2);
  unsigned short* w2h = (unsigned short*)alloc((size_t)PK_T2 * 2);
  unsigned short* w2l = (unsigned short*)alloc((size_t)PK_T2 * 2);
  unsigned short* v0h = (unsigned short*)alloc((size_t)PK_U0 * 2);
  unsigned short* v0l = (unsigned short*)alloc((size_t)PK_U0 * 2);
  unsigned short* v1h = (unsigned short*)alloc((size_t)PK_U1 * 2);
  unsigned short* v1l = (unsigned short*)alloc((size_t)PK_U1 * 2);
  unsigned short* v2h = (unsigned short*)alloc((size_t)PK_U2 * 2);
  unsigned short* v2l = (unsigned short*)alloc((size_t)PK_U2 * 2);

  float* xout = (float*)d_out;                 // (B,64,512)
  float* pos3 = xout + (size_t)B * 64 * 512;   // (B,64,3)

  const float r2a = (float)(0.05 * 0.05);
  const float r2b = (float)(0.3 * 0.3);
  const float r2c = (float)(0.5 * 0.5);

  l1_kernel<<<8 + 4096 + PK_BLOCKS, 256, 0, stream>>>(
      pos, pos1, feat, emb, pid, x0, s3w0, s3w1, s3w2, s2w0, s2w1, s2w2,
      w0h, w0l, w1h, w1l, w2h, w2l, v0h, v0l, v1h, v1l, v2h, v2l);
  l2_kernel<<<8 + 8192, 256, 0, stream>>>(pos1, pos2, pos, r2a, nbr1, cnt1);
  l3_kernel<<<8 + 2048 + 8192, 256, 0, stream>>>(
      pos2, pos3, r2b, nbr2, cnt2, pos1, x0, pos, nbr1, cnt1,
      s1w0, s1b0, s1w1, s1b1, s1w2, s1b2, x1);
  l4_kernel<<<512 + 2048, 256, 0, stream>>>(
      pos2, pos3, r2c, nbr3, cnt3, x1, pos1, nbr2, cnt2,
      v0h, s2b0, v1h, s2b1, v2h, s2b2, x2);
  conv3_mfma<<<B * 64, 256, 0, stream>>>(x2, pos2, pos3, nbr3, cnt3,
                                         w0h, s3b0, w1h, s3b1, w2h, s3b2, xout);
}